// Round 1
// baseline (1653.353 us; speedup 1.0000x reference)
//
#include <hip/hip_runtime.h>
#include <cstdint>
#include <cstddef>
#include <cmath>

constexpr int B = 8;
constexpr int N0 = 1024;

// ---------------- prep: transpose pc [B,3,N] -> pts [B,N,3], feat0 [B,N,4] ----------------
__global__ __launch_bounds__(256) void k_prep(const float* __restrict__ pc,
                                              float* __restrict__ pts,
                                              float* __restrict__ feat0) {
  int idx = blockIdx.x * blockDim.x + threadIdx.x;
  if (idx >= B * N0) return;
  int b = idx / N0, i = idx - b * N0;
  float x = pc[(b * 3 + 0) * N0 + i];
  float y = pc[(b * 3 + 1) * N0 + i];
  float z = pc[(b * 3 + 2) * N0 + i];
  pts[idx * 3 + 0] = x; pts[idx * 3 + 1] = y; pts[idx * 3 + 2] = z;
  feat0[idx * 4 + 0] = x; feat0[idx * 4 + 1] = y; feat0[idx * 4 + 2] = z; feat0[idx * 4 + 3] = 1.0f;
}

// ---------------- stage 1: sparse Gaussian contraction ----------------
// S[bi, l*Cin + c] = sum_j e_l(i,j) * feat[b,j,c]
// block = max(64,Cin) threads (thread = channel c), one block per (b,i).
__global__ __launch_bounds__(256) void k_econtract(const float* __restrict__ pts,
                                                   const float* __restrict__ feat,
                                                   float* __restrict__ S,
                                                   int N, int Cin, int b0) {
  extern __shared__ float lds[];               // [blockDim.x][28] e27 rows
  __shared__ unsigned long long kmask[4];
  const int t = threadIdx.x;
  const int TJ = blockDim.x;
  const int bi = blockIdx.x;                   // chunk-local (b-b0)*N + i
  const int b = b0 + bi / N;
  const int i = bi - (bi / N) * N;
  const float px = pts[((size_t)b * N + i) * 3 + 0];
  const float py = pts[((size_t)b * N + i) * 3 + 1];
  const float pz = pts[((size_t)b * N + i) * 3 + 2];
  const int c = t;
  const bool cact = c < Cin;
  float acc[27];
#pragma unroll
  for (int l = 0; l < 27; ++l) acc[l] = 0.f;
  const int nw = TJ >> 6;

  for (int j0 = 0; j0 < N; j0 += TJ) {
    const int j = j0 + t;
    int kj = 0;
    if (j < N) {
      float dx = px - pts[((size_t)b * N + j) * 3 + 0];
      float dy = py - pts[((size_t)b * N + j) * 3 + 1];
      float dz = pz - pts[((size_t)b * N + j) * 3 + 2];
      float d2 = dx * dx + dy * dy + dz * dz;
      // keep iff max_l e_l >= ~e^-30: (||d||-T*sqrt3)^2*512 <= 30  ->  d2 <= 0.1228
      if (d2 <= 0.1228f) {
        kj = 1;
        float base = __expf(-512.f * d2);
        // Gd[-1] = exp(64*dd - 2), Gd[+1] = exp(-64*dd - 2)   (T=1/16, inv=512)
        float gx[3] = {__expf(64.f * dx - 2.f), 1.f, __expf(-64.f * dx - 2.f)};
        float gy[3] = {__expf(64.f * dy - 2.f), 1.f, __expf(-64.f * dy - 2.f)};
        float gz[3] = {__expf(64.f * dz - 2.f), 1.f, __expf(-64.f * dz - 2.f)};
        float* er = &lds[t * 28];
#pragma unroll
        for (int a = 0; a < 3; ++a) {
          float ba = base * gx[a];
#pragma unroll
          for (int b2 = 0; b2 < 3; ++b2) {
            float bab = ba * gy[b2];
#pragma unroll
            for (int c2 = 0; c2 < 3; ++c2) er[a * 9 + b2 * 3 + c2] = bab * gz[c2];
          }
        }
      }
    }
    unsigned long long mb = __ballot(kj);
    if ((t & 63) == 0) kmask[t >> 6] = mb;
    __syncthreads();
    for (int w = 0; w < nw; ++w) {
      unsigned long long m = kmask[w];
      while (m) {
        int jj = (w << 6) + __ffsll((long long)m) - 1;
        m &= m - 1;
        float fv = cact ? feat[((size_t)b * N + (j0 + jj)) * Cin + c] : 0.f;
        const float* er = &lds[jj * 28];
#pragma unroll
        for (int l = 0; l < 27; ++l) acc[l] = fmaf(er[l], fv, acc[l]);
      }
    }
    __syncthreads();
  }
  if (cact) {
    size_t row = (size_t)bi * 27 * Cin;
#pragma unroll
    for (int l = 0; l < 27; ++l) S[row + (size_t)l * Cin + c] = acc[l];
  }
}

// ---------------- stage 2: GEMM  out = relu(scale * S@W + bias) ----------------
template <int BM, int BN, int TM, int TN, int TH>
__global__ __launch_bounds__(TH) void k_gemm(const float* __restrict__ A,
                                             const float* __restrict__ Bw,
                                             const float* __restrict__ bias,
                                             float* __restrict__ out,
                                             int M, int K, int CN, float scale) {
  constexpr int BK = 32;
  __shared__ float As[BK][BM + 4];
  __shared__ float Bs[BK][BN + 4];
  const int t = threadIdx.x;
  const int tx = t % (BN / TN);
  const int ty = t / (BN / TN);
  const int m0 = blockIdx.x * BM;
  const int n0 = blockIdx.y * BN;
  float acc[TM][TN];
#pragma unroll
  for (int i = 0; i < TM; ++i)
#pragma unroll
    for (int j = 0; j < TN; ++j) acc[i][j] = 0.f;

  for (int k0 = 0; k0 < K; k0 += BK) {
    constexpr int AV = BM * BK / (TH * 4);
#pragma unroll
    for (int v = 0; v < AV; ++v) {
      int p = t + v * TH;
      int row = p / (BK / 4);
      int kk = (p % (BK / 4)) * 4;
      int gk = k0 + kk;
      const float* src = A + (size_t)(m0 + row) * K + gk;
      float4 val;
      if (gk + 3 < K) val = *(const float4*)src;
      else {
        val.x = gk + 0 < K ? src[0] : 0.f;
        val.y = gk + 1 < K ? src[1] : 0.f;
        val.z = gk + 2 < K ? src[2] : 0.f;
        val.w = gk + 3 < K ? src[3] : 0.f;
      }
      As[kk + 0][row] = val.x; As[kk + 1][row] = val.y;
      As[kk + 2][row] = val.z; As[kk + 3][row] = val.w;
    }
    constexpr int BVC = BK * BN / (TH * 4);
#pragma unroll
    for (int v = 0; v < BVC; ++v) {
      int p = t + v * TH;
      int kk = p / (BN / 4);
      int oq = (p % (BN / 4)) * 4;
      int gk = k0 + kk;
      float4 val = make_float4(0.f, 0.f, 0.f, 0.f);
      if (gk < K) val = *(const float4*)(Bw + (size_t)gk * CN + n0 + oq);
      *(float4*)&Bs[kk][oq] = val;
    }
    __syncthreads();
#pragma unroll
    for (int kk = 0; kk < BK; ++kk) {
      float a[TM], bb[TN];
#pragma unroll
      for (int u = 0; u < TM; ++u) a[u] = As[kk][ty * TM + u];
#pragma unroll
      for (int u = 0; u < TN; ++u) bb[u] = Bs[kk][tx * TN + u];
#pragma unroll
      for (int i = 0; i < TM; ++i)
#pragma unroll
        for (int j = 0; j < TN; ++j) acc[i][j] = fmaf(a[i], bb[j], acc[i][j]);
    }
    __syncthreads();
  }
#pragma unroll
  for (int i = 0; i < TM; ++i) {
    int m = m0 + ty * TM + i;
#pragma unroll
    for (int j = 0; j < TN; ++j) {
      int n = n0 + tx * TN + j;
      float v = fmaf(acc[i][j], scale, bias[n]);
      out[(size_t)m * CN + n] = fmaxf(v, 0.f);
    }
  }
}

// ---------------- FPS (1 wave per batch) ----------------
template <int N>
__global__ __launch_bounds__(64) void k_fps(const float* __restrict__ pts,
                                            float* __restrict__ centers, int m) {
  constexpr int NQ = N / 64;
  const int b = blockIdx.x;
  const int lane = threadIdx.x;
  const float* P = pts + (size_t)b * N * 3;
  float qx[NQ], qy[NQ], qz[NQ], d[NQ];
  float x0 = P[0], y0 = P[1], z0 = P[2];
#pragma unroll
  for (int q = 0; q < NQ; ++q) {
    int j = lane + q * 64;
    float x = P[j * 3 + 0], y = P[j * 3 + 1], z = P[j * 3 + 2];
    qx[q] = x; qy[q] = y; qz[q] = z;
    float dx = __fsub_rn(x, x0), dy = __fsub_rn(y, y0), dz = __fsub_rn(z, z0);
    d[q] = __fadd_rn(__fadd_rn(__fmul_rn(dx, dx), __fmul_rn(dy, dy)), __fmul_rn(dz, dz));
  }
  if (lane == 0) {
    centers[(size_t)b * m * 3 + 0] = x0;
    centers[(size_t)b * m * 3 + 1] = y0;
    centers[(size_t)b * m * 3 + 2] = z0;
  }
  for (int it = 1; it < m; ++it) {
    float bv = -1.f; int bj = 0x7fffffff;
#pragma unroll
    for (int q = 0; q < NQ; ++q) {
      if (d[q] > bv) { bv = d[q]; bj = lane + q * 64; }
    }
#pragma unroll
    for (int off = 32; off >= 1; off >>= 1) {
      float ov = __shfl_xor(bv, off);
      int oj = __shfl_xor(bj, off);
      if (ov > bv || (ov == bv && oj < bj)) { bv = ov; bj = oj; }
    }
    float cx = P[bj * 3 + 0], cy = P[bj * 3 + 1], cz = P[bj * 3 + 2];
    if (lane == 0) {
      centers[((size_t)b * m + it) * 3 + 0] = cx;
      centers[((size_t)b * m + it) * 3 + 1] = cy;
      centers[((size_t)b * m + it) * 3 + 2] = cz;
    }
#pragma unroll
    for (int q = 0; q < NQ; ++q) {
      float dx = __fsub_rn(qx[q], cx), dy = __fsub_rn(qy[q], cy), dz = __fsub_rn(qz[q], cz);
      float nd = __fadd_rn(__fadd_rn(__fmul_rn(dx, dx), __fmul_rn(dy, dy)), __fmul_rn(dz, dz));
      d[q] = fminf(d[q], nd);
    }
  }
}

// ---------------- nearest-center assignment ----------------
__global__ __launch_bounds__(256) void k_assign(const float* __restrict__ pts,
                                                const float* __restrict__ centers,
                                                int* __restrict__ assign, int N, int m) {
  int idx = blockIdx.x * blockDim.x + threadIdx.x;
  if (idx >= B * N) return;
  int b = idx / N;
  float px = pts[(size_t)idx * 3 + 0], py = pts[(size_t)idx * 3 + 1], pz = pts[(size_t)idx * 3 + 2];
  float best = 3.4e38f; int bk = 0;
  for (int k = 0; k < m; ++k) {
    float dx = __fsub_rn(px, centers[((size_t)b * m + k) * 3 + 0]);
    float dy = __fsub_rn(py, centers[((size_t)b * m + k) * 3 + 1]);
    float dz = __fsub_rn(pz, centers[((size_t)b * m + k) * 3 + 2]);
    float dd = __fadd_rn(__fadd_rn(__fmul_rn(dx, dx), __fmul_rn(dy, dy)), __fmul_rn(dz, dz));
    if (dd < best) { best = dd; bk = k; }
  }
  assign[idx] = bk;
}

__global__ __launch_bounds__(256) void k_fill(float* __restrict__ p, int n, float v) {
  int i = blockIdx.x * blockDim.x + threadIdx.x;
  if (i < n) p[i] = v;
}

// segment max via int atomicMax (values are post-relu >= 0; init = -inf bits)
__global__ __launch_bounds__(256) void k_segmax(const float* __restrict__ feat,
                                                const int* __restrict__ assign,
                                                float* __restrict__ pooled,
                                                int N, int m, int C) {
  int idx = blockIdx.x * blockDim.x + threadIdx.x;
  if (idx >= B * N * C) return;
  int b = idx / (N * C);
  int r = idx - b * N * C;
  int i = r / C;
  int c = r - i * C;
  int a = assign[b * N + i];
  atomicMax((int*)&pooled[((size_t)b * m + a) * C + c], __float_as_int(feat[idx]));
}

// ---------------- FC (+optional batch-norm over batch dim + relu) ----------------
template <int K, int COUT, bool BNR>
__global__ __launch_bounds__(256) void k_fc(const float* __restrict__ x,
                                            const float* __restrict__ w,
                                            const float* __restrict__ g,
                                            const float* __restrict__ be,
                                            float* __restrict__ out) {
  __shared__ float ys[8][33];
  int t = threadIdx.x;
  int n = t >> 5, cl = t & 31;
  int c = blockIdx.x * 32 + cl;
  float acc = 0.f;
  if (c < COUT) {
    const float* xr = x + n * K;
    for (int k = 0; k < K; ++k) acc = fmaf(xr[k], w[(size_t)k * COUT + c], acc);
  }
  ys[n][cl] = acc;
  __syncthreads();
  if (c >= COUT) return;
  if (BNR) {
    float mu = 0.f;
#pragma unroll
    for (int q = 0; q < 8; ++q) mu += ys[q][cl];
    mu *= 0.125f;
    float var = 0.f;
#pragma unroll
    for (int q = 0; q < 8; ++q) { float dv = ys[q][cl] - mu; var = fmaf(dv, dv, var); }
    var *= 0.125f;
    float rs = 1.f / sqrtf(var + 1e-5f);
    float v = g[c] * (acc - mu) * rs + be[c];
    out[n * COUT + c] = fmaxf(v, 0.f);
  } else {
    out[n * COUT + c] = acc + be[c];
  }
}

// ---------------- launcher ----------------
extern "C" void kernel_launch(void* const* d_in, const int* in_sizes, int n_in,
                              void* d_out, int out_size, void* d_ws, size_t ws_size,
                              hipStream_t stream) {
  (void)in_sizes; (void)n_in; (void)out_size;
  const float* pc = (const float*)d_in[0];
  const float* Wc[6]; const float* bc[6];
  for (int l = 0; l < 6; ++l) { Wc[l] = (const float*)d_in[1 + 2 * l]; bc[l] = (const float*)d_in[2 + 2 * l]; }
  const float* w1 = (const float*)d_in[13];
  const float* g1 = (const float*)d_in[14];
  const float* be1 = (const float*)d_in[15];
  const float* w2 = (const float*)d_in[16];
  const float* g2 = (const float*)d_in[17];
  const float* be2 = (const float*)d_in[18];
  const float* w3 = (const float*)d_in[19];
  const float* b3 = (const float*)d_in[20];

  float* ws = (float*)d_ws;
  size_t o = 0;
  auto A = [&](size_t n) { size_t r = o; o += (n + 63) & ~(size_t)63; return r; };
  const size_t PTS0 = A((size_t)B * 1024 * 3);
  const size_t PTS1 = A((size_t)B * 256 * 3);
  const size_t PTS2 = A((size_t)B * 64 * 3);
  const size_t PTS3 = A((size_t)B * 3);
  const size_t F0  = A((size_t)B * 1024 * 4);
  const size_t FB1 = A((size_t)B * 1024 * 64);
  const size_t FB2 = A((size_t)B * 1024 * 64);
  const size_t FB3 = A((size_t)B * 256 * 64);
  const size_t FB4 = A((size_t)B * 256 * 128);
  const size_t FB5 = A((size_t)B * 256 * 128);
  const size_t FB6 = A((size_t)B * 64 * 128);
  const size_t FB7 = A((size_t)B * 64 * 256);
  const size_t FB8 = A((size_t)B * 64 * 1024);
  const size_t FB9 = A((size_t)B * 1024);
  const size_t ASSIGN = A((size_t)B * 1024);
  const size_t Y1 = A((size_t)8 * 512);
  const size_t Y2 = A((size_t)8 * 256);
  const size_t SOFF = o;
  const size_t avail = (ws_size / 4 > SOFF) ? ws_size / 4 - SOFF : 1;

  k_prep<<<dim3((B * N0 + 255) / 256), dim3(256), 0, stream>>>(pc, ws + PTS0, ws + F0);

  auto conv = [&](size_t ptsOff, size_t finOff, size_t foutOff, int N, int Cin, int Cout,
                  const float* W, const float* bias) {
    int cb = B;
    while (cb > 1 && (size_t)cb * N * 27 * Cin > avail) --cb;
    for (int b0 = 0; b0 < B; b0 += cb) {
      int nb = (B - b0 < cb) ? (B - b0) : cb;
      int M = nb * N;
      int blk = Cin <= 64 ? 64 : Cin;
      size_t sh = (size_t)blk * 28 * sizeof(float);
      k_econtract<<<dim3(M), dim3(blk), sh, stream>>>(ws + ptsOff, ws + finOff, ws + SOFF, N, Cin, b0);
      float scale = 1.f / (float)N;
      int K = 27 * Cin;
      float* outp = ws + foutOff + (size_t)b0 * N * Cout;
      if (M % 64 == 0 && M >= 4096) {
        k_gemm<64, 32, 4, 2, 256><<<dim3(M / 64, Cout / 32), dim3(256), 0, stream>>>(
            ws + SOFF, W, bias, outp, M, K, Cout, scale);
      } else {
        k_gemm<16, 64, 2, 4, 128><<<dim3(M / 16, Cout / 64), dim3(128), 0, stream>>>(
            ws + SOFF, W, bias, outp, M, K, Cout, scale);
      }
    }
  };

  // block 1
  conv(PTS0, F0, FB1, 1024, 4, 64, Wc[0], bc[0]);
  conv(PTS0, FB1, FB2, 1024, 64, 64, Wc[1], bc[1]);
  k_fps<1024><<<dim3(B), dim3(64), 0, stream>>>(ws + PTS0, ws + PTS1, 256);
  k_assign<<<dim3((B * 1024 + 255) / 256), dim3(256), 0, stream>>>(ws + PTS0, ws + PTS1, (int*)(ws + ASSIGN), 1024, 256);
  k_fill<<<dim3((B * 256 * 64 + 255) / 256), dim3(256), 0, stream>>>(ws + FB3, B * 256 * 64, -HUGE_VALF);
  k_segmax<<<dim3((B * 1024 * 64 + 255) / 256), dim3(256), 0, stream>>>(ws + FB2, (int*)(ws + ASSIGN), ws + FB3, 1024, 256, 64);
  // block 2
  conv(PTS1, FB3, FB4, 256, 64, 128, Wc[2], bc[2]);
  conv(PTS1, FB4, FB5, 256, 128, 128, Wc[3], bc[3]);
  k_fps<256><<<dim3(B), dim3(64), 0, stream>>>(ws + PTS1, ws + PTS2, 64);
  k_assign<<<dim3((B * 256 + 255) / 256), dim3(256), 0, stream>>>(ws + PTS1, ws + PTS2, (int*)(ws + ASSIGN), 256, 64);
  k_fill<<<dim3((B * 64 * 128 + 255) / 256), dim3(256), 0, stream>>>(ws + FB6, B * 64 * 128, -HUGE_VALF);
  k_segmax<<<dim3((B * 256 * 128 + 255) / 256), dim3(256), 0, stream>>>(ws + FB5, (int*)(ws + ASSIGN), ws + FB6, 256, 64, 128);
  // block 3
  conv(PTS2, FB6, FB7, 64, 128, 256, Wc[4], bc[4]);
  conv(PTS2, FB7, FB8, 64, 256, 1024, Wc[5], bc[5]);
  k_fps<64><<<dim3(B), dim3(64), 0, stream>>>(ws + PTS2, ws + PTS3, 1);
  k_assign<<<dim3((B * 64 + 255) / 256), dim3(256), 0, stream>>>(ws + PTS2, ws + PTS3, (int*)(ws + ASSIGN), 64, 1);
  k_fill<<<dim3((B * 1024 + 255) / 256), dim3(256), 0, stream>>>(ws + FB9, B * 1024, -HUGE_VALF);
  k_segmax<<<dim3((B * 64 * 1024 + 255) / 256), dim3(256), 0, stream>>>(ws + FB8, (int*)(ws + ASSIGN), ws + FB9, 64, 1, 1024);
  // FC head
  k_fc<1024, 512, true><<<dim3(512 / 32), dim3(256), 0, stream>>>(ws + FB9, w1, g1, be1, ws + Y1);
  k_fc<512, 256, true><<<dim3(256 / 32), dim3(256), 0, stream>>>(ws + Y1, w2, g2, be2, ws + Y2);
  k_fc<256, 40, false><<<dim3(2), dim3(256), 0, stream>>>(ws + Y2, w3, nullptr, b3, (float*)d_out);
}

// Round 2
// 851.941 us; speedup vs baseline: 1.9407x; 1.9407x over previous
//
#include <hip/hip_runtime.h>
#include <cstdint>
#include <cstddef>
#include <cmath>

constexpr int B = 8;
constexpr int N0 = 1024;
using u16 = unsigned short;

typedef __bf16 bf16x8 __attribute__((ext_vector_type(8)));
typedef float f32x4 __attribute__((ext_vector_type(4)));

__device__ inline u16 f2bf(float x) {
  unsigned u = __float_as_uint(x);
  return (u16)((u + 0x7fffu + ((u >> 16) & 1u)) >> 16);
}
__device__ inline float bf2f(u16 h) { return __uint_as_float(((unsigned)h) << 16); }

// ---------------- prep: transpose pc [B,3,N] -> pts [B,N,3], feat0 [B,N,4] ----------------
__global__ __launch_bounds__(256) void k_prep(const float* __restrict__ pc,
                                              float* __restrict__ pts,
                                              float* __restrict__ feat0) {
  int idx = blockIdx.x * blockDim.x + threadIdx.x;
  if (idx >= B * N0) return;
  int b = idx / N0, i = idx - b * N0;
  float x = pc[(b * 3 + 0) * N0 + i];
  float y = pc[(b * 3 + 1) * N0 + i];
  float z = pc[(b * 3 + 2) * N0 + i];
  pts[idx * 3 + 0] = x; pts[idx * 3 + 1] = y; pts[idx * 3 + 2] = z;
  feat0[idx * 4 + 0] = x; feat0[idx * 4 + 1] = y; feat0[idx * 4 + 2] = z; feat0[idx * 4 + 3] = 1.0f;
}

// ---------------- stage 1: sparse Gaussian contraction -> split bf16 S ----------------
// S[row, l*Cin + c] = sum_j e_l(i,j) * feat[b,j,c]; row = block-local m index.
__global__ __launch_bounds__(256) void k_econtract(const float* __restrict__ pts,
                                                   const float* __restrict__ feat,
                                                   u16* __restrict__ Shi,
                                                   u16* __restrict__ Slo,
                                                   int N, int Cin, int Kpad, int mbase) {
  extern __shared__ float lds[];               // [blockDim.x][28] e27 rows
  __shared__ unsigned long long kmask[4];
  const int t = threadIdx.x;
  const int TJ = blockDim.x;
  const int g = mbase + blockIdx.x;            // global row in [0, B*N)
  const int b = g / N;
  const int i = g - b * N;
  const float px = pts[((size_t)b * N + i) * 3 + 0];
  const float py = pts[((size_t)b * N + i) * 3 + 1];
  const float pz = pts[((size_t)b * N + i) * 3 + 2];
  const int c = t;
  const bool cact = c < Cin;
  float acc[27];
#pragma unroll
  for (int l = 0; l < 27; ++l) acc[l] = 0.f;
  const int nw = TJ >> 6;

  for (int j0 = 0; j0 < N; j0 += TJ) {
    const int j = j0 + t;
    int kj = 0;
    if (j < N) {
      float dx = px - pts[((size_t)b * N + j) * 3 + 0];
      float dy = py - pts[((size_t)b * N + j) * 3 + 1];
      float dz = pz - pts[((size_t)b * N + j) * 3 + 2];
      float d2 = dx * dx + dy * dy + dz * dz;
      if (d2 <= 0.1228f) {                     // keep iff max_l e_l >= ~e^-30
        kj = 1;
        float base = __expf(-512.f * d2);
        float gx[3] = {__expf(64.f * dx - 2.f), 1.f, __expf(-64.f * dx - 2.f)};
        float gy[3] = {__expf(64.f * dy - 2.f), 1.f, __expf(-64.f * dy - 2.f)};
        float gz[3] = {__expf(64.f * dz - 2.f), 1.f, __expf(-64.f * dz - 2.f)};
        float* er = &lds[t * 28];
#pragma unroll
        for (int a = 0; a < 3; ++a) {
          float ba = base * gx[a];
#pragma unroll
          for (int b2 = 0; b2 < 3; ++b2) {
            float bab = ba * gy[b2];
#pragma unroll
            for (int c2 = 0; c2 < 3; ++c2) er[a * 9 + b2 * 3 + c2] = bab * gz[c2];
          }
        }
      }
    }
    unsigned long long mb = __ballot(kj);
    if ((t & 63) == 0) kmask[t >> 6] = mb;
    __syncthreads();
    for (int w = 0; w < nw; ++w) {
      unsigned long long m = kmask[w];
      while (m) {
        int jj = (w << 6) + __ffsll((long long)m) - 1;
        m &= m - 1;
        float fv = cact ? feat[((size_t)b * N + (j0 + jj)) * Cin + c] : 0.f;
        const float* er = &lds[jj * 28];
#pragma unroll
        for (int l = 0; l < 27; ++l) acc[l] = fmaf(er[l], fv, acc[l]);
      }
    }
    __syncthreads();
  }
  if (cact) {
    size_t row = (size_t)blockIdx.x * Kpad;
#pragma unroll
    for (int l = 0; l < 27; ++l) {
      float v = acc[l];
      u16 h = f2bf(v);
      u16 lo = f2bf(v - bf2f(h));
      Shi[row + (size_t)l * Cin + c] = h;
      Slo[row + (size_t)l * Cin + c] = lo;
    }
  }
}

// ---------------- W split+transpose: W[K][Cout] fp32 -> Wt_{hi,lo}[ncur][Kpad] bf16 ----------------
__global__ __launch_bounds__(256) void k_wsplit(const float* __restrict__ W,
                                                u16* __restrict__ Whi, u16* __restrict__ Wlo,
                                                int K, int Kpad, int Cout, int nbase) {
  __shared__ float tile[32][65];
  const int t = threadIdx.x;
  const int k0 = blockIdx.x * 32, n0 = blockIdx.y * 64;
#pragma unroll
  for (int v = 0; v < 2; ++v) {
    int kk = (t >> 4) + v * 16;
    int nn = (t & 15) * 4;
    int gk = k0 + kk;
    float4 val = make_float4(0.f, 0.f, 0.f, 0.f);
    if (gk < K) val = *(const float4*)(W + (size_t)gk * Cout + nbase + n0 + nn);
    tile[kk][nn + 0] = val.x; tile[kk][nn + 1] = val.y;
    tile[kk][nn + 2] = val.z; tile[kk][nn + 3] = val.w;
  }
  __syncthreads();
  const int n_ = t >> 2, kq = (t & 3) * 8;
  union { u16 u[8]; uint4 v; } Uh, Ul;
#pragma unroll
  for (int j = 0; j < 8; ++j) {
    float x = tile[kq + j][n_];
    u16 h = f2bf(x);
    Uh.u[j] = h;
    Ul.u[j] = f2bf(x - bf2f(h));
  }
  size_t o = (size_t)(n0 + n_) * Kpad + k0 + kq;
  *(uint4*)(Whi + o) = Uh.v;
  *(uint4*)(Wlo + o) = Ul.v;
}

// ---------------- stage 2: MFMA GEMM  out = relu(scale * S@W + bias) ----------------
// A = S split [M][Kpad], B = Wt split [N][Kpad] (pre-transposed). 3-term bf16 split.
// grid = (ncur/64, mcur/32): blockIdx.x = n-tile so wgid%8 groups n-tiles per XCD (W L2 reuse).
__global__ __launch_bounds__(256) void k_gemm_mfma(const u16* __restrict__ Shi,
                                                   const u16* __restrict__ Slo,
                                                   const u16* __restrict__ Whi,
                                                   const u16* __restrict__ Wlo,
                                                   const float* __restrict__ bias,
                                                   float* __restrict__ out,
                                                   int Kpad, int Nstride, float scale) {
  __shared__ u16 As[2][32][40];   // [hi/lo][row m][k] pad to 40 (80B rows)
  __shared__ u16 Bs[2][64][40];   // [hi/lo][row n][k]
  const int t = threadIdx.x;
  const int nb = blockIdx.x * 64;
  const int m0 = blockIdx.y * 32;
  const int l = t & 63, w = t >> 6;
  const int wm = (w >> 1) * 16, wn = (w & 1) * 32;
  const int la = l & 15, lg = l >> 4;
  const int ar = t >> 3, akq = (t & 7) * 4;
  const int bn = t >> 2, bkq = (t & 3) * 8;
  const size_t aBase = (size_t)(m0 + ar) * Kpad + akq;
  const size_t bBase = (size_t)(nb + bn) * Kpad + bkq;
  f32x4 acc0 = {0.f, 0.f, 0.f, 0.f}, acc1 = {0.f, 0.f, 0.f, 0.f};

  for (int k0 = 0; k0 < Kpad; k0 += 32) {
    *(ushort4*)&As[0][ar][akq] = *(const ushort4*)(Shi + aBase + k0);
    *(ushort4*)&As[1][ar][akq] = *(const ushort4*)(Slo + aBase + k0);
    *(uint4*)&Bs[0][bn][bkq] = *(const uint4*)(Whi + bBase + k0);
    *(uint4*)&Bs[1][bn][bkq] = *(const uint4*)(Wlo + bBase + k0);
    __syncthreads();
    bf16x8 ah = *(const bf16x8*)&As[0][wm + la][lg * 8];
    bf16x8 al = *(const bf16x8*)&As[1][wm + la][lg * 8];
    bf16x8 bh0 = *(const bf16x8*)&Bs[0][wn + la][lg * 8];
    bf16x8 bl0 = *(const bf16x8*)&Bs[1][wn + la][lg * 8];
    bf16x8 bh1 = *(const bf16x8*)&Bs[0][wn + 16 + la][lg * 8];
    bf16x8 bl1 = *(const bf16x8*)&Bs[1][wn + 16 + la][lg * 8];
    acc0 = __builtin_amdgcn_mfma_f32_16x16x32_bf16(ah, bh0, acc0, 0, 0, 0);
    acc1 = __builtin_amdgcn_mfma_f32_16x16x32_bf16(ah, bh1, acc1, 0, 0, 0);
    acc0 = __builtin_amdgcn_mfma_f32_16x16x32_bf16(al, bh0, acc0, 0, 0, 0);
    acc1 = __builtin_amdgcn_mfma_f32_16x16x32_bf16(al, bh1, acc1, 0, 0, 0);
    acc0 = __builtin_amdgcn_mfma_f32_16x16x32_bf16(ah, bl0, acc0, 0, 0, 0);
    acc1 = __builtin_amdgcn_mfma_f32_16x16x32_bf16(ah, bl1, acc1, 0, 0, 0);
    __syncthreads();
  }
#pragma unroll
  for (int r = 0; r < 4; ++r) {
    int gm = m0 + wm + lg * 4 + r;
    int gn0 = nb + wn + la;
    float v0 = fmaf(acc0[r], scale, bias[gn0]);
    out[(size_t)gm * Nstride + gn0] = fmaxf(v0, 0.f);
    int gn1 = gn0 + 16;
    float v1 = fmaf(acc1[r], scale, bias[gn1]);
    out[(size_t)gm * Nstride + gn1] = fmaxf(v1, 0.f);
  }
}

// ---------------- FPS (256 threads per batch, fused update+argmax) ----------------
template <int N>
__global__ __launch_bounds__(256) void k_fps(const float* __restrict__ pts,
                                             float* __restrict__ centers, int m) {
  constexpr int NQ = (N + 255) / 256;
  __shared__ float bvs[4];
  __shared__ int bjs[4];
  const int b = blockIdx.x;
  const int t = threadIdx.x, lane = t & 63, w = t >> 6;
  const float* P = pts + (size_t)b * N * 3;
  float qx[NQ], qy[NQ], qz[NQ], d[NQ];
  float x0 = P[0], y0 = P[1], z0 = P[2];
  float bv = -1.f; int bj = 0x7fffffff;
#pragma unroll
  for (int q = 0; q < NQ; ++q) {
    int j = t + q * 256;
    d[q] = -1.f;
    if (j < N) {
      float x = P[j * 3 + 0], y = P[j * 3 + 1], z = P[j * 3 + 2];
      qx[q] = x; qy[q] = y; qz[q] = z;
      float dx = __fsub_rn(x, x0), dy = __fsub_rn(y, y0), dz = __fsub_rn(z, z0);
      d[q] = __fadd_rn(__fadd_rn(__fmul_rn(dx, dx), __fmul_rn(dy, dy)), __fmul_rn(dz, dz));
      if (d[q] > bv) { bv = d[q]; bj = j; }
    }
  }
  if (t == 0) {
    centers[(size_t)b * m * 3 + 0] = x0;
    centers[(size_t)b * m * 3 + 1] = y0;
    centers[(size_t)b * m * 3 + 2] = z0;
  }
  for (int it = 1; it < m; ++it) {
#pragma unroll
    for (int off = 32; off >= 1; off >>= 1) {
      float ov = __shfl_xor(bv, off);
      int oj = __shfl_xor(bj, off);
      if (ov > bv || (ov == bv && oj < bj)) { bv = ov; bj = oj; }
    }
    __syncthreads();
    if (lane == 0) { bvs[w] = bv; bjs[w] = bj; }
    __syncthreads();
    float gbv = bvs[0]; int gbj = bjs[0];
#pragma unroll
    for (int u = 1; u < 4; ++u) {
      float ov = bvs[u]; int oj = bjs[u];
      if (ov > gbv || (ov == gbv && oj < gbj)) { gbv = ov; gbj = oj; }
    }
    float cx = P[gbj * 3 + 0], cy = P[gbj * 3 + 1], cz = P[gbj * 3 + 2];
    if (t == 0) {
      centers[((size_t)b * m + it) * 3 + 0] = cx;
      centers[((size_t)b * m + it) * 3 + 1] = cy;
      centers[((size_t)b * m + it) * 3 + 2] = cz;
    }
    bv = -1.f; bj = 0x7fffffff;
#pragma unroll
    for (int q = 0; q < NQ; ++q) {
      int j = t + q * 256;
      if (j < N) {
        float dx = __fsub_rn(qx[q], cx), dy = __fsub_rn(qy[q], cy), dz = __fsub_rn(qz[q], cz);
        float nd = __fadd_rn(__fadd_rn(__fmul_rn(dx, dx), __fmul_rn(dy, dy)), __fmul_rn(dz, dz));
        float dn = fminf(d[q], nd);
        d[q] = dn;
        if (dn > bv) { bv = dn; bj = j; }
      }
    }
  }
}

// ---------------- nearest-center assignment ----------------
__global__ __launch_bounds__(256) void k_assign(const float* __restrict__ pts,
                                                const float* __restrict__ centers,
                                                int* __restrict__ assign, int N, int m) {
  int idx = blockIdx.x * blockDim.x + threadIdx.x;
  if (idx >= B * N) return;
  int b = idx / N;
  float px = pts[(size_t)idx * 3 + 0], py = pts[(size_t)idx * 3 + 1], pz = pts[(size_t)idx * 3 + 2];
  float best = 3.4e38f; int bk = 0;
  for (int k = 0; k < m; ++k) {
    float dx = __fsub_rn(px, centers[((size_t)b * m + k) * 3 + 0]);
    float dy = __fsub_rn(py, centers[((size_t)b * m + k) * 3 + 1]);
    float dz = __fsub_rn(pz, centers[((size_t)b * m + k) * 3 + 2]);
    float dd = __fadd_rn(__fadd_rn(__fmul_rn(dx, dx), __fmul_rn(dy, dy)), __fmul_rn(dz, dz));
    if (dd < best) { best = dd; bk = k; }
  }
  assign[idx] = bk;
}

__global__ __launch_bounds__(256) void k_fill(float* __restrict__ p, int n, float v) {
  int i = blockIdx.x * blockDim.x + threadIdx.x;
  if (i < n) p[i] = v;
}

__global__ __launch_bounds__(256) void k_fillz(unsigned* __restrict__ p, int n) {
  int i = blockIdx.x * blockDim.x + threadIdx.x;
  if (i < n) p[i] = 0u;
}

// segment max via int atomicMax (values are post-relu >= 0; init = -inf bits)
__global__ __launch_bounds__(256) void k_segmax(const float* __restrict__ feat,
                                                const int* __restrict__ assign,
                                                float* __restrict__ pooled,
                                                int N, int m, int C) {
  int idx = blockIdx.x * blockDim.x + threadIdx.x;
  if (idx >= B * N * C) return;
  int b = idx / (N * C);
  int r = idx - b * N * C;
  int i = r / C;
  int c = r - i * C;
  int a = assign[b * N + i];
  atomicMax((int*)&pooled[((size_t)b * m + a) * C + c], __float_as_int(feat[idx]));
}

// ---------------- FC (+optional batch-norm over batch dim + relu) ----------------
template <int K, int COUT, bool BNR>
__global__ __launch_bounds__(256) void k_fc(const float* __restrict__ x,
                                            const float* __restrict__ w,
                                            const float* __restrict__ g,
                                            const float* __restrict__ be,
                                            float* __restrict__ out) {
  __shared__ float ys[8][33];
  int t = threadIdx.x;
  int n = t >> 5, cl = t & 31;
  int c = blockIdx.x * 32 + cl;
  float acc = 0.f;
  if (c < COUT) {
    const float* xr = x + n * K;
    for (int k = 0; k < K; ++k) acc = fmaf(xr[k], w[(size_t)k * COUT + c], acc);
  }
  ys[n][cl] = acc;
  __syncthreads();
  if (c >= COUT) return;
  if (BNR) {
    float mu = 0.f;
#pragma unroll
    for (int q = 0; q < 8; ++q) mu += ys[q][cl];
    mu *= 0.125f;
    float var = 0.f;
#pragma unroll
    for (int q = 0; q < 8; ++q) { float dv = ys[q][cl] - mu; var = fmaf(dv, dv, var); }
    var *= 0.125f;
    float rs = 1.f / sqrtf(var + 1e-5f);
    float v = g[c] * (acc - mu) * rs + be[c];
    out[n * COUT + c] = fmaxf(v, 0.f);
  } else {
    out[n * COUT + c] = acc + be[c];
  }
}

// ---------------- launcher ----------------
extern "C" void kernel_launch(void* const* d_in, const int* in_sizes, int n_in,
                              void* d_out, int out_size, void* d_ws, size_t ws_size,
                              hipStream_t stream) {
  (void)in_sizes; (void)n_in; (void)out_size;
  const float* pc = (const float*)d_in[0];
  const float* Wc[6]; const float* bc[6];
  for (int l = 0; l < 6; ++l) { Wc[l] = (const float*)d_in[1 + 2 * l]; bc[l] = (const float*)d_in[2 + 2 * l]; }
  const float* w1 = (const float*)d_in[13];
  const float* g1 = (const float*)d_in[14];
  const float* be1 = (const float*)d_in[15];
  const float* w2 = (const float*)d_in[16];
  const float* g2 = (const float*)d_in[17];
  const float* be2 = (const float*)d_in[18];
  const float* w3 = (const float*)d_in[19];
  const float* b3 = (const float*)d_in[20];

  float* ws = (float*)d_ws;
  size_t o = 0;
  auto A = [&](size_t n) { size_t r = o; o += (n + 63) & ~(size_t)63; return r; };
  const size_t PTS0 = A((size_t)B * 1024 * 3);
  const size_t PTS1 = A((size_t)B * 256 * 3);
  const size_t PTS2 = A((size_t)B * 64 * 3);
  const size_t PTS3 = A((size_t)B * 3);
  const size_t F0  = A((size_t)B * 1024 * 4);
  const size_t FB1 = A((size_t)B * 1024 * 64);
  const size_t FB2 = A((size_t)B * 1024 * 64);
  const size_t FB3 = A((size_t)B * 256 * 64);
  const size_t FB4 = A((size_t)B * 256 * 128);
  const size_t FB5 = A((size_t)B * 256 * 128);
  const size_t FB6 = A((size_t)B * 64 * 128);
  const size_t FB7 = A((size_t)B * 64 * 256);
  const size_t FB8 = A((size_t)B * 64 * 1024);
  const size_t FB9 = A((size_t)B * 1024);
  const size_t ASSIGN = A((size_t)B * 1024);
  const size_t Y1 = A((size_t)8 * 512);
  const size_t Y2 = A((size_t)8 * 256);
  const size_t dynB = o * sizeof(float);   // dynamic area base (bytes), 256B aligned

  k_prep<<<dim3((B * N0 + 255) / 256), dim3(256), 0, stream>>>(pc, ws + PTS0, ws + F0);

  auto conv = [&](size_t ptsOff, size_t finOff, size_t foutOff, int Npts, int Cin, int Cout,
                  const float* W, const float* bias) {
    const int M = B * Npts;
    const int K = 27 * Cin;
    const int Kpad = (K + 31) & ~31;
    const size_t availB = (ws_size > dynB) ? ws_size - dynB : 0;
    int NCc = Cout;
    while (NCc > 128 && (size_t)NCc * Kpad * 4 + (size_t)M * Kpad * 4 > availB) NCc >>= 1;
    while (NCc > 64 && (size_t)NCc * Kpad * 4 + (size_t)32 * Kpad * 4 > availB) NCc >>= 1;
    const size_t wtB = (size_t)NCc * Kpad * 4;
    const size_t sB = (availB > wtB) ? availB - wtB : 0;
    long mc = (long)(sB / ((size_t)Kpad * 4)) & ~31L;
    int Mc = (int)((mc < (long)M) ? mc : (long)M);
    if (Mc < 32) Mc = 32;
    u16* Shi = (u16*)((char*)d_ws + dynB);
    u16* Slo = Shi + (size_t)Mc * Kpad;
    u16* Whi = Shi + (size_t)2 * Mc * Kpad;
    u16* Wlo = Whi + (size_t)NCc * Kpad;
    const int nch = (Cout + NCc - 1) / NCc;
    const int mch = (M + Mc - 1) / Mc;
    const float scale = 1.f / (float)Npts;
    const int blk = (Cin <= 64) ? 64 : Cin;
    const size_t sh = (size_t)blk * 28 * sizeof(float);
    for (int nc = 0; nc < nch; ++nc) {
      const int nb0 = nc * NCc;
      const int ncur = ((Cout - nb0) < NCc) ? (Cout - nb0) : NCc;
      k_wsplit<<<dim3(Kpad / 32, ncur / 64), dim3(256), 0, stream>>>(W, Whi, Wlo, K, Kpad, Cout, nb0);
      for (int mcb = 0; mcb < mch; ++mcb) {
        const int mb0 = mcb * Mc;
        const int mcur = ((M - mb0) < Mc) ? (M - mb0) : Mc;
        if (nc == 0 || mch > 1) {
          if (Kpad != K) {
            int nfill = Mc * Kpad;  // hi+lo contiguous, as uints
            k_fillz<<<dim3((nfill + 255) / 256), dim3(256), 0, stream>>>((unsigned*)Shi, nfill);
          }
          k_econtract<<<dim3(mcur), dim3(blk), sh, stream>>>(ws + ptsOff, ws + finOff, Shi, Slo,
                                                             Npts, Cin, Kpad, mb0);
        }
        float* outp = ws + foutOff + (size_t)mb0 * Cout + nb0;
        k_gemm_mfma<<<dim3(ncur / 64, mcur / 32), dim3(256), 0, stream>>>(
            Shi, Slo, Whi, Wlo, bias + nb0, outp, Kpad, Cout, scale);
      }
    }
  };

  // block 1
  conv(PTS0, F0, FB1, 1024, 4, 64, Wc[0], bc[0]);
  conv(PTS0, FB1, FB2, 1024, 64, 64, Wc[1], bc[1]);
  k_fps<1024><<<dim3(B), dim3(256), 0, stream>>>(ws + PTS0, ws + PTS1, 256);
  k_assign<<<dim3((B * 1024 + 255) / 256), dim3(256), 0, stream>>>(ws + PTS0, ws + PTS1, (int*)(ws + ASSIGN), 1024, 256);
  k_fill<<<dim3((B * 256 * 64 + 255) / 256), dim3(256), 0, stream>>>(ws + FB3, B * 256 * 64, -HUGE_VALF);
  k_segmax<<<dim3((B * 1024 * 64 + 255) / 256), dim3(256), 0, stream>>>(ws + FB2, (int*)(ws + ASSIGN), ws + FB3, 1024, 256, 64);
  // block 2
  conv(PTS1, FB3, FB4, 256, 64, 128, Wc[2], bc[2]);
  conv(PTS1, FB4, FB5, 256, 128, 128, Wc[3], bc[3]);
  k_fps<256><<<dim3(B), dim3(256), 0, stream>>>(ws + PTS1, ws + PTS2, 64);
  k_assign<<<dim3((B * 256 + 255) / 256), dim3(256), 0, stream>>>(ws + PTS1, ws + PTS2, (int*)(ws + ASSIGN), 256, 64);
  k_fill<<<dim3((B * 64 * 128 + 255) / 256), dim3(256), 0, stream>>>(ws + FB6, B * 64 * 128, -HUGE_VALF);
  k_segmax<<<dim3((B * 256 * 128 + 255) / 256), dim3(256), 0, stream>>>(ws + FB5, (int*)(ws + ASSIGN), ws + FB6, 256, 64, 128);
  // block 3
  conv(PTS2, FB6, FB7, 64, 128, 256, Wc[4], bc[4]);
  conv(PTS2, FB7, FB8, 64, 256, 1024, Wc[5], bc[5]);
  k_fps<64><<<dim3(B), dim3(256), 0, stream>>>(ws + PTS2, ws + PTS3, 1);
  k_assign<<<dim3((B * 64 + 255) / 256), dim3(256), 0, stream>>>(ws + PTS2, ws + PTS3, (int*)(ws + ASSIGN), 64, 1);
  k_fill<<<dim3((B * 1024 + 255) / 256), dim3(256), 0, stream>>>(ws + FB9, B * 1024, -HUGE_VALF);
  k_segmax<<<dim3((B * 64 * 1024 + 255) / 256), dim3(256), 0, stream>>>(ws + FB8, (int*)(ws + ASSIGN), ws + FB9, 64, 1, 1024);
  // FC head
  k_fc<1024, 512, true><<<dim3(512 / 32), dim3(256), 0, stream>>>(ws + FB9, w1, g1, be1, ws + Y1);
  k_fc<512, 256, true><<<dim3(256 / 32), dim3(256), 0, stream>>>(ws + Y1, w2, g2, be2, ws + Y2);
  k_fc<256, 40, false><<<dim3(2), dim3(256), 0, stream>>>(ws + Y2, w3, nullptr, b3, (float*)d_out);
}

// Round 3
// 693.124 us; speedup vs baseline: 2.3854x; 1.2291x over previous
//
#include <hip/hip_runtime.h>
#include <cstdint>
#include <cstddef>
#include <cmath>

constexpr int B = 8;
constexpr int N0 = 1024;
constexpr int CAP = 128;   // max neighbors within r=0.35 of N(0,1) points (expected ~12)
using u16 = unsigned short;

typedef __bf16 bf16x8 __attribute__((ext_vector_type(8)));
typedef float f32x4 __attribute__((ext_vector_type(4)));

__device__ inline u16 f2bf(float x) {
  unsigned u = __float_as_uint(x);
  return (u16)((u + 0x7fffu + ((u >> 16) & 1u)) >> 16);
}
__device__ inline float bf2f(u16 h) { return __uint_as_float(((unsigned)h) << 16); }

// ---------------- prep: transpose pc [B,3,N] -> pts [B,N,3], feat0 [B,N,4] ----------------
__global__ __launch_bounds__(256) void k_prep(const float* __restrict__ pc,
                                              float* __restrict__ pts,
                                              float* __restrict__ feat0) {
  int idx = blockIdx.x * blockDim.x + threadIdx.x;
  if (idx >= B * N0) return;
  int b = idx / N0, i = idx - b * N0;
  float x = pc[(b * 3 + 0) * N0 + i];
  float y = pc[(b * 3 + 1) * N0 + i];
  float z = pc[(b * 3 + 2) * N0 + i];
  pts[idx * 3 + 0] = x; pts[idx * 3 + 1] = y; pts[idx * 3 + 2] = z;
  feat0[idx * 4 + 0] = x; feat0[idx * 4 + 1] = y; feat0[idx * 4 + 2] = z; feat0[idx * 4 + 3] = 1.0f;
}

// ---------------- pair lists: per row, compacted j with d2 <= cutoff ----------------
__global__ __launch_bounds__(256) void k_pairs(const float* __restrict__ pts,
                                               int* __restrict__ pidx, int* __restrict__ pcnt,
                                               int N) {
  const int r = blockIdx.x * 4 + (threadIdx.x >> 6);   // global row in [0, B*N)
  const int lane = threadIdx.x & 63;
  const int b = r / N;
  const float px = pts[(size_t)r * 3 + 0];
  const float py = pts[(size_t)r * 3 + 1];
  const float pz = pts[(size_t)r * 3 + 2];
  int* row = pidx + (size_t)r * CAP;
  int base = 0;
  for (int j0 = 0; j0 < N; j0 += 64) {
    int j = j0 + lane;
    float dx = px - pts[((size_t)b * N + j) * 3 + 0];
    float dy = py - pts[((size_t)b * N + j) * 3 + 1];
    float dz = pz - pts[((size_t)b * N + j) * 3 + 2];
    float d2 = dx * dx + dy * dy + dz * dz;
    bool keep = d2 <= 0.1228f;                 // max_l e_l >= ~e^-30
    unsigned long long mk = __ballot(keep);
    int pos = __popcll(mk & ((1ull << lane) - 1ull));
    if (keep) { int s = base + pos; if (s < CAP) row[s] = j; }
    base += __popcll(mk);
  }
  if (lane == 0) pcnt[r] = base < CAP ? base : CAP;
}

// ---------------- stage 1: pair-list Gaussian contraction -> split bf16 S ----------------
__global__ void k_econtract2(const float* __restrict__ pts, const float* __restrict__ feat,
                             const int* __restrict__ pidx, const int* __restrict__ pcnt,
                             u16* __restrict__ Shi, u16* __restrict__ Slo,
                             int N, int Cin, int K, int Kpad, int mbase) {
  const int g = mbase + blockIdx.x;            // global row in [0, B*N)
  const int b = g / N;
  const int t = threadIdx.x;
  const bool cact = t < Cin;
  const float px = pts[(size_t)g * 3 + 0];
  const float py = pts[(size_t)g * 3 + 1];
  const float pz = pts[(size_t)g * 3 + 2];
  float acc[27];
#pragma unroll
  for (int l = 0; l < 27; ++l) acc[l] = 0.f;
  const int n = pcnt[g];
  const int* row = pidx + (size_t)g * CAP;
  for (int p = 0; p < n; ++p) {
    int j = row[p];
    size_t jb = (size_t)b * N + j;
    float dx = px - pts[jb * 3 + 0];
    float dy = py - pts[jb * 3 + 1];
    float dz = pz - pts[jb * 3 + 2];
    float d2 = dx * dx + dy * dy + dz * dz;
    float base_ = __expf(-512.f * d2);
    float gxv[3] = {__expf(64.f * dx - 2.f), 1.f, __expf(-64.f * dx - 2.f)};
    float gyv[3] = {__expf(64.f * dy - 2.f), 1.f, __expf(-64.f * dy - 2.f)};
    float gzv[3] = {__expf(64.f * dz - 2.f), 1.f, __expf(-64.f * dz - 2.f)};
    float fv = cact ? feat[jb * Cin + t] : 0.f;
#pragma unroll
    for (int a = 0; a < 3; ++a) {
      float ba = base_ * gxv[a];
#pragma unroll
      for (int b2 = 0; b2 < 3; ++b2) {
        float bab = ba * gyv[b2];
#pragma unroll
        for (int c2 = 0; c2 < 3; ++c2) {
          int l = a * 9 + b2 * 3 + c2;
          acc[l] = fmaf(bab * gzv[c2], fv, acc[l]);
        }
      }
    }
  }
  size_t rowo = (size_t)blockIdx.x * Kpad;
  if (cact) {
#pragma unroll
    for (int l = 0; l < 27; ++l) {
      float v = acc[l];
      u16 h = f2bf(v);
      u16 lo = f2bf(v - bf2f(h));
      Shi[rowo + (size_t)l * Cin + t] = h;
      Slo[rowo + (size_t)l * Cin + t] = lo;
    }
  }
  if (Kpad > K && t >= Cin && t < Cin + (Kpad - K)) {
    size_t po = rowo + K + (t - Cin);
    Shi[po] = 0; Slo[po] = 0;
  }
}

// ---------------- W split+transpose: W[K][Cout] fp32 -> Wt_{hi,lo}[ncur][Kpad] bf16 ----------------
__global__ __launch_bounds__(256) void k_wsplit(const float* __restrict__ W,
                                                u16* __restrict__ Whi, u16* __restrict__ Wlo,
                                                int K, int Kpad, int Cout, int nbase) {
  __shared__ float tile[32][65];
  const int t = threadIdx.x;
  const int k0 = blockIdx.x * 32, n0 = blockIdx.y * 64;
#pragma unroll
  for (int v = 0; v < 2; ++v) {
    int kk = (t >> 4) + v * 16;
    int nn = (t & 15) * 4;
    int gk = k0 + kk;
    float4 val = make_float4(0.f, 0.f, 0.f, 0.f);
    if (gk < K) val = *(const float4*)(W + (size_t)gk * Cout + nbase + n0 + nn);
    tile[kk][nn + 0] = val.x; tile[kk][nn + 1] = val.y;
    tile[kk][nn + 2] = val.z; tile[kk][nn + 3] = val.w;
  }
  __syncthreads();
  const int n_ = t >> 2, kq = (t & 3) * 8;
  union { u16 u[8]; uint4 v; } Uh, Ul;
#pragma unroll
  for (int j = 0; j < 8; ++j) {
    float x = tile[kq + j][n_];
    u16 h = f2bf(x);
    Uh.u[j] = h;
    Ul.u[j] = f2bf(x - bf2f(h));
  }
  size_t o = (size_t)(n0 + n_) * Kpad + k0 + kq;
  *(uint4*)(Whi + o) = Uh.v;
  *(uint4*)(Wlo + o) = Ul.v;
}

// ---------------- stage 2: MFMA GEMM  out = relu(scale * S@W + bias) ----------------
__global__ __launch_bounds__(256) void k_gemm_mfma(const u16* __restrict__ Shi,
                                                   const u16* __restrict__ Slo,
                                                   const u16* __restrict__ Whi,
                                                   const u16* __restrict__ Wlo,
                                                   const float* __restrict__ bias,
                                                   float* __restrict__ out,
                                                   int Kpad, int Nstride, float scale) {
  __shared__ u16 As[2][32][40];
  __shared__ u16 Bs[2][64][40];
  const int t = threadIdx.x;
  const int nb = blockIdx.x * 64;
  const int m0 = blockIdx.y * 32;
  const int l = t & 63, w = t >> 6;
  const int wm = (w >> 1) * 16, wn = (w & 1) * 32;
  const int la = l & 15, lg = l >> 4;
  const int ar = t >> 3, akq = (t & 7) * 4;
  const int bn = t >> 2, bkq = (t & 3) * 8;
  const size_t aBase = (size_t)(m0 + ar) * Kpad + akq;
  const size_t bBase = (size_t)(nb + bn) * Kpad + bkq;
  f32x4 acc0 = {0.f, 0.f, 0.f, 0.f}, acc1 = {0.f, 0.f, 0.f, 0.f};

  for (int k0 = 0; k0 < Kpad; k0 += 32) {
    *(ushort4*)&As[0][ar][akq] = *(const ushort4*)(Shi + aBase + k0);
    *(ushort4*)&As[1][ar][akq] = *(const ushort4*)(Slo + aBase + k0);
    *(uint4*)&Bs[0][bn][bkq] = *(const uint4*)(Whi + bBase + k0);
    *(uint4*)&Bs[1][bn][bkq] = *(const uint4*)(Wlo + bBase + k0);
    __syncthreads();
    bf16x8 ah = *(const bf16x8*)&As[0][wm + la][lg * 8];
    bf16x8 al = *(const bf16x8*)&As[1][wm + la][lg * 8];
    bf16x8 bh0 = *(const bf16x8*)&Bs[0][wn + la][lg * 8];
    bf16x8 bl0 = *(const bf16x8*)&Bs[1][wn + la][lg * 8];
    bf16x8 bh1 = *(const bf16x8*)&Bs[0][wn + 16 + la][lg * 8];
    bf16x8 bl1 = *(const bf16x8*)&Bs[1][wn + 16 + la][lg * 8];
    acc0 = __builtin_amdgcn_mfma_f32_16x16x32_bf16(ah, bh0, acc0, 0, 0, 0);
    acc1 = __builtin_amdgcn_mfma_f32_16x16x32_bf16(ah, bh1, acc1, 0, 0, 0);
    acc0 = __builtin_amdgcn_mfma_f32_16x16x32_bf16(al, bh0, acc0, 0, 0, 0);
    acc1 = __builtin_amdgcn_mfma_f32_16x16x32_bf16(al, bh1, acc1, 0, 0, 0);
    acc0 = __builtin_amdgcn_mfma_f32_16x16x32_bf16(ah, bl0, acc0, 0, 0, 0);
    acc1 = __builtin_amdgcn_mfma_f32_16x16x32_bf16(ah, bl1, acc1, 0, 0, 0);
    __syncthreads();
  }
#pragma unroll
  for (int r = 0; r < 4; ++r) {
    int gm = m0 + wm + lg * 4 + r;
    int gn0 = nb + wn + la;
    float v0 = fmaf(acc0[r], scale, bias[gn0]);
    out[(size_t)gm * Nstride + gn0] = fmaxf(v0, 0.f);
    int gn1 = gn0 + 16;
    float v1 = fmaf(acc1[r], scale, bias[gn1]);
    out[(size_t)gm * Nstride + gn1] = fmaxf(v1, 0.f);
  }
}

// ---------------- FPS: 1 wave per batch, register-resident, DPP argmax ----------------
template <int CTRL>
__device__ __forceinline__ void dppmax(unsigned& hi, unsigned& lo) {
  unsigned thi = (unsigned)__builtin_amdgcn_update_dpp(0, (int)hi, CTRL, 0xF, 0xF, true);
  unsigned tlo = (unsigned)__builtin_amdgcn_update_dpp(0, (int)lo, CTRL, 0xF, 0xF, true);
  bool g = (thi > hi) || (thi == hi && tlo > lo);
  hi = g ? thi : hi;
  lo = g ? tlo : lo;
}

template <int N>
__global__ __launch_bounds__(64) void k_fps(const float* __restrict__ pts,
                                            float* __restrict__ centers, int m) {
  constexpr int NQ = N / 64;
  const int b = blockIdx.x;
  const int lane = threadIdx.x;
  const float* P = pts + (size_t)b * N * 3;
  float qx[NQ], qy[NQ], qz[NQ], d[NQ];
  float x0 = P[0], y0 = P[1], z0 = P[2];
  float lbest = -1.f; int lj = 0;
#pragma unroll
  for (int q = 0; q < NQ; ++q) {
    int j = lane + q * 64;
    float x = P[j * 3 + 0], y = P[j * 3 + 1], z = P[j * 3 + 2];
    qx[q] = x; qy[q] = y; qz[q] = z;
    float dx = __fsub_rn(x, x0), dy = __fsub_rn(y, y0), dz = __fsub_rn(z, z0);
    float dd = __fadd_rn(__fadd_rn(__fmul_rn(dx, dx), __fmul_rn(dy, dy)), __fmul_rn(dz, dz));
    d[q] = dd;
    bool g = dd > lbest; lbest = g ? dd : lbest; lj = g ? j : lj;
  }
  if (lane == 0) {
    centers[(size_t)b * m * 3 + 0] = x0;
    centers[(size_t)b * m * 3 + 1] = y0;
    centers[(size_t)b * m * 3 + 2] = z0;
  }
  for (int it = 1; it < m; ++it) {
    // packed argmax key: max d, tie -> min j
    unsigned hi = __float_as_uint(lbest), lo = ~(unsigned)lj;
    dppmax<0xB1>(hi, lo);   // quad_perm [1,0,3,2]  (xor 1)
    dppmax<0x4E>(hi, lo);   // quad_perm [2,3,0,1]  (xor 2)
    dppmax<0x141>(hi, lo);  // row_half_mirror      (cross quad-pair)
    dppmax<0x140>(hi, lo);  // row_mirror           (cross 8-group)
    dppmax<0x142>(hi, lo);  // row_bcast:15
    dppmax<0x143>(hi, lo);  // row_bcast:31  -> lane 63 has global max
    int wj = ~__builtin_amdgcn_readlane((int)lo, 63);
    int qsel = wj >> 6, sl = wj & 63;
    float sx = qx[0], sy = qy[0], sz = qz[0];
#pragma unroll
    for (int q = 1; q < NQ; ++q) {
      bool e = (q == qsel);
      sx = e ? qx[q] : sx; sy = e ? qy[q] : sy; sz = e ? qz[q] : sz;
    }
    float cx = __uint_as_float((unsigned)__builtin_amdgcn_readlane((int)__float_as_uint(sx), sl));
    float cy = __uint_as_float((unsigned)__builtin_amdgcn_readlane((int)__float_as_uint(sy), sl));
    float cz = __uint_as_float((unsigned)__builtin_amdgcn_readlane((int)__float_as_uint(sz), sl));
    if (lane == 0) {
      centers[((size_t)b * m + it) * 3 + 0] = cx;
      centers[((size_t)b * m + it) * 3 + 1] = cy;
      centers[((size_t)b * m + it) * 3 + 2] = cz;
    }
    lbest = -1.f; lj = 0;
#pragma unroll
    for (int q = 0; q < NQ; ++q) {
      int j = lane + q * 64;
      float dx = __fsub_rn(qx[q], cx), dy = __fsub_rn(qy[q], cy), dz = __fsub_rn(qz[q], cz);
      float nd = __fadd_rn(__fadd_rn(__fmul_rn(dx, dx), __fmul_rn(dy, dy)), __fmul_rn(dz, dz));
      float dn = fminf(d[q], nd);
      d[q] = dn;
      bool g = dn > lbest; lbest = g ? dn : lbest; lj = g ? j : lj;
    }
  }
}

// ---------------- nearest-center assignment ----------------
__global__ __launch_bounds__(256) void k_assign(const float* __restrict__ pts,
                                                const float* __restrict__ centers,
                                                int* __restrict__ assign, int N, int m) {
  int idx = blockIdx.x * blockDim.x + threadIdx.x;
  if (idx >= B * N) return;
  int b = idx / N;
  float px = pts[(size_t)idx * 3 + 0], py = pts[(size_t)idx * 3 + 1], pz = pts[(size_t)idx * 3 + 2];
  float best = 3.4e38f; int bk = 0;
  for (int k = 0; k < m; ++k) {
    float dx = __fsub_rn(px, centers[((size_t)b * m + k) * 3 + 0]);
    float dy = __fsub_rn(py, centers[((size_t)b * m + k) * 3 + 1]);
    float dz = __fsub_rn(pz, centers[((size_t)b * m + k) * 3 + 2]);
    float dd = __fadd_rn(__fadd_rn(__fmul_rn(dx, dx), __fmul_rn(dy, dy)), __fmul_rn(dz, dz));
    if (dd < best) { best = dd; bk = k; }
  }
  assign[idx] = bk;
}

__global__ __launch_bounds__(256) void k_fill(float* __restrict__ p, int n, float v) {
  int i = blockIdx.x * blockDim.x + threadIdx.x;
  if (i < n) p[i] = v;
}

// segment max via int atomicMax (values are post-relu >= 0; init = -inf bits)
__global__ __launch_bounds__(256) void k_segmax(const float* __restrict__ feat,
                                                const int* __restrict__ assign,
                                                float* __restrict__ pooled,
                                                int N, int m, int C) {
  int idx = blockIdx.x * blockDim.x + threadIdx.x;
  if (idx >= B * N * C) return;
  int b = idx / (N * C);
  int r = idx - b * N * C;
  int i = r / C;
  int c = r - i * C;
  int a = assign[b * N + i];
  atomicMax((int*)&pooled[((size_t)b * m + a) * C + c], __float_as_int(feat[idx]));
}

// ---------------- FC (+optional batch-norm over batch dim + relu) ----------------
template <int K, int COUT, bool BNR>
__global__ __launch_bounds__(256) void k_fc(const float* __restrict__ x,
                                            const float* __restrict__ w,
                                            const float* __restrict__ g,
                                            const float* __restrict__ be,
                                            float* __restrict__ out) {
  __shared__ float ys[8][33];
  int t = threadIdx.x;
  int n = t >> 5, cl = t & 31;
  int c = blockIdx.x * 32 + cl;
  float acc = 0.f;
  if (c < COUT) {
    const float* xr = x + n * K;
    float a0 = 0.f, a1 = 0.f, a2 = 0.f, a3 = 0.f;
    for (int k = 0; k < K; k += 4) {
      a0 = fmaf(xr[k + 0], w[(size_t)(k + 0) * COUT + c], a0);
      a1 = fmaf(xr[k + 1], w[(size_t)(k + 1) * COUT + c], a1);
      a2 = fmaf(xr[k + 2], w[(size_t)(k + 2) * COUT + c], a2);
      a3 = fmaf(xr[k + 3], w[(size_t)(k + 3) * COUT + c], a3);
    }
    acc = (a0 + a1) + (a2 + a3);
  }
  ys[n][cl] = acc;
  __syncthreads();
  if (c >= COUT) return;
  if (BNR) {
    float mu = 0.f;
#pragma unroll
    for (int q = 0; q < 8; ++q) mu += ys[q][cl];
    mu *= 0.125f;
    float var = 0.f;
#pragma unroll
    for (int q = 0; q < 8; ++q) { float dv = ys[q][cl] - mu; var = fmaf(dv, dv, var); }
    var *= 0.125f;
    float rs = 1.f / sqrtf(var + 1e-5f);
    float v = g[c] * (acc - mu) * rs + be[c];
    out[n * COUT + c] = fmaxf(v, 0.f);
  } else {
    out[n * COUT + c] = acc + be[c];
  }
}

// ---------------- launcher ----------------
extern "C" void kernel_launch(void* const* d_in, const int* in_sizes, int n_in,
                              void* d_out, int out_size, void* d_ws, size_t ws_size,
                              hipStream_t stream) {
  (void)in_sizes; (void)n_in; (void)out_size;
  const float* pc = (const float*)d_in[0];
  const float* Wc[6]; const float* bc[6];
  for (int l = 0; l < 6; ++l) { Wc[l] = (const float*)d_in[1 + 2 * l]; bc[l] = (const float*)d_in[2 + 2 * l]; }
  const float* w1 = (const float*)d_in[13];
  const float* g1 = (const float*)d_in[14];
  const float* be1 = (const float*)d_in[15];
  const float* w2 = (const float*)d_in[16];
  const float* g2 = (const float*)d_in[17];
  const float* be2 = (const float*)d_in[18];
  const float* w3 = (const float*)d_in[19];
  const float* b3 = (const float*)d_in[20];

  float* ws = (float*)d_ws;
  size_t o = 0;
  auto A = [&](size_t n) { size_t r = o; o += (n + 63) & ~(size_t)63; return r; };
  const size_t PTS0 = A((size_t)B * 1024 * 3);
  const size_t PTS1 = A((size_t)B * 256 * 3);
  const size_t PTS2 = A((size_t)B * 64 * 3);
  const size_t PTS3 = A((size_t)B * 3);
  const size_t F0  = A((size_t)B * 1024 * 4);
  const size_t FB1 = A((size_t)B * 1024 * 64);
  const size_t FB2 = A((size_t)B * 1024 * 64);
  const size_t FB3 = A((size_t)B * 256 * 64);
  const size_t FB4 = A((size_t)B * 256 * 128);
  const size_t FB5 = A((size_t)B * 256 * 128);
  const size_t FB6 = A((size_t)B * 64 * 128);
  const size_t FB7 = A((size_t)B * 64 * 256);
  const size_t FB8 = A((size_t)B * 64 * 1024);
  const size_t FB9 = A((size_t)B * 1024);
  const size_t ASSIGN = A((size_t)B * 1024);
  const size_t Y1 = A((size_t)8 * 512);
  const size_t Y2 = A((size_t)8 * 256);
  const size_t PIDX = A((size_t)B * 1024 * CAP);
  const size_t PCNT = A((size_t)B * 1024);
  const size_t dynB = o * sizeof(float);

  int* pidx = (int*)(ws + PIDX);
  int* pcnt = (int*)(ws + PCNT);

  k_prep<<<dim3((B * N0 + 255) / 256), dim3(256), 0, stream>>>(pc, ws + PTS0, ws + F0);

  auto conv = [&](size_t ptsOff, size_t finOff, size_t foutOff, int Npts, int Cin, int Cout,
                  const float* W, const float* bias) {
    const int M = B * Npts;
    const int K = 27 * Cin;
    const int Kpad = (K + 31) & ~31;
    const size_t availB = (ws_size > dynB) ? ws_size - dynB : 0;
    int NCc = Cout;
    while (NCc > 128 && (size_t)NCc * Kpad * 4 + (size_t)M * Kpad * 4 > availB) NCc >>= 1;
    while (NCc > 64 && (size_t)NCc * Kpad * 4 + (size_t)32 * Kpad * 4 > availB) NCc >>= 1;
    const size_t wtB = (size_t)NCc * Kpad * 4;
    const size_t sB = (availB > wtB) ? availB - wtB : 0;
    long mc = (long)(sB / ((size_t)Kpad * 4)) & ~31L;
    int Mc = (int)((mc < (long)M) ? mc : (long)M);
    if (Mc < 32) Mc = 32;
    u16* Shi = (u16*)((char*)d_ws + dynB);
    u16* Slo = Shi + (size_t)Mc * Kpad;
    u16* Whi = Shi + (size_t)2 * Mc * Kpad;
    u16* Wlo = Whi + (size_t)NCc * Kpad;
    const int nch = (Cout + NCc - 1) / NCc;
    const int mch = (M + Mc - 1) / Mc;
    const float scale = 1.f / (float)Npts;
    const int blk = (Cin <= 64) ? 64 : Cin;
    auto econ = [&](int mb0, int mcur) {
      k_econtract2<<<dim3(mcur), dim3(blk), 0, stream>>>(ws + ptsOff, ws + finOff, pidx, pcnt,
                                                         Shi, Slo, Npts, Cin, K, Kpad, mb0);
    };
    auto wsp = [&](int nb0, int ncur) {
      k_wsplit<<<dim3(Kpad / 32, ncur / 64), dim3(256), 0, stream>>>(W, Whi, Wlo, K, Kpad, Cout, nb0);
    };
    auto gem = [&](int nb0, int ncur, int mb0, int mcur) {
      float* outp = ws + foutOff + (size_t)mb0 * Cout + nb0;
      k_gemm_mfma<<<dim3(ncur / 64, mcur / 32), dim3(256), 0, stream>>>(
          Shi, Slo, Whi, Wlo, bias + nb0, outp, Kpad, Cout, scale);
    };
    if (mch == 1) {
      econ(0, M);
      for (int nc = 0; nc < nch; ++nc) {
        int nb0 = nc * NCc;
        int ncur = ((Cout - nb0) < NCc) ? (Cout - nb0) : NCc;
        wsp(nb0, ncur);
        gem(nb0, ncur, 0, M);
      }
    } else if (nch == 1) {
      wsp(0, Cout);
      for (int mcb = 0; mcb < mch; ++mcb) {
        int mb0 = mcb * Mc;
        int mcur = ((M - mb0) < Mc) ? (M - mb0) : Mc;
        econ(mb0, mcur);
        gem(0, Cout, mb0, mcur);
      }
    } else {
      for (int nc = 0; nc < nch; ++nc) {
        int nb0 = nc * NCc;
        int ncur = ((Cout - nb0) < NCc) ? (Cout - nb0) : NCc;
        wsp(nb0, ncur);
        for (int mcb = 0; mcb < mch; ++mcb) {
          int mb0 = mcb * Mc;
          int mcur = ((M - mb0) < Mc) ? (M - mb0) : Mc;
          econ(mb0, mcur);
          gem(nb0, ncur, mb0, mcur);
        }
      }
    }
  };

  // ---- level 0 ----
  k_pairs<<<dim3(B * 1024 / 4), dim3(256), 0, stream>>>(ws + PTS0, pidx, pcnt, 1024);
  conv(PTS0, F0, FB1, 1024, 4, 64, Wc[0], bc[0]);
  conv(PTS0, FB1, FB2, 1024, 64, 64, Wc[1], bc[1]);
  k_fps<1024><<<dim3(B), dim3(64), 0, stream>>>(ws + PTS0, ws + PTS1, 256);
  k_assign<<<dim3((B * 1024 + 255) / 256), dim3(256), 0, stream>>>(ws + PTS0, ws + PTS1, (int*)(ws + ASSIGN), 1024, 256);
  k_fill<<<dim3((B * 256 * 64 + 255) / 256), dim3(256), 0, stream>>>(ws + FB3, B * 256 * 64, -HUGE_VALF);
  k_segmax<<<dim3((B * 1024 * 64 + 255) / 256), dim3(256), 0, stream>>>(ws + FB2, (int*)(ws + ASSIGN), ws + FB3, 1024, 256, 64);
  // ---- level 1 ----
  k_pairs<<<dim3(B * 256 / 4), dim3(256), 0, stream>>>(ws + PTS1, pidx, pcnt, 256);
  conv(PTS1, FB3, FB4, 256, 64, 128, Wc[2], bc[2]);
  conv(PTS1, FB4, FB5, 256, 128, 128, Wc[3], bc[3]);
  k_fps<256><<<dim3(B), dim3(64), 0, stream>>>(ws + PTS1, ws + PTS2, 64);
  k_assign<<<dim3((B * 256 + 255) / 256), dim3(256), 0, stream>>>(ws + PTS1, ws + PTS2, (int*)(ws + ASSIGN), 256, 64);
  k_fill<<<dim3((B * 64 * 128 + 255) / 256), dim3(256), 0, stream>>>(ws + FB6, B * 64 * 128, -HUGE_VALF);
  k_segmax<<<dim3((B * 256 * 128 + 255) / 256), dim3(256), 0, stream>>>(ws + FB5, (int*)(ws + ASSIGN), ws + FB6, 256, 64, 128);
  // ---- level 2 ----
  k_pairs<<<dim3(B * 64 / 4), dim3(256), 0, stream>>>(ws + PTS2, pidx, pcnt, 64);
  conv(PTS2, FB6, FB7, 64, 128, 256, Wc[4], bc[4]);
  conv(PTS2, FB7, FB8, 64, 256, 1024, Wc[5], bc[5]);
  k_fps<64><<<dim3(B), dim3(64), 0, stream>>>(ws + PTS2, ws + PTS3, 1);
  k_assign<<<dim3((B * 64 + 255) / 256), dim3(256), 0, stream>>>(ws + PTS2, ws + PTS3, (int*)(ws + ASSIGN), 64, 1);
  k_fill<<<dim3((B * 1024 + 255) / 256), dim3(256), 0, stream>>>(ws + FB9, B * 1024, -HUGE_VALF);
  k_segmax<<<dim3((B * 64 * 1024 + 255) / 256), dim3(256), 0, stream>>>(ws + FB8, (int*)(ws + ASSIGN), ws + FB9, 64, 1, 1024);
  // ---- FC head ----
  k_fc<1024, 512, true><<<dim3(512 / 32), dim3(256), 0, stream>>>(ws + FB9, w1, g1, be1, ws + Y1);
  k_fc<512, 256, true><<<dim3(256 / 32), dim3(256), 0, stream>>>(ws + Y1, w2, g2, be2, ws + Y2);
  k_fc<256, 40, false><<<dim3(2), dim3(256), 0, stream>>>(ws + Y2, w3, nullptr, b3, (float*)d_out);
}

// Round 4
// 632.233 us; speedup vs baseline: 2.6151x; 1.0963x over previous
//
#include <hip/hip_runtime.h>
#include <cstdint>
#include <cstddef>
#include <cmath>

constexpr int B = 8;
constexpr int N0 = 1024;
constexpr int CAP = 128;
using u16 = unsigned short;

typedef __bf16 bf16x8 __attribute__((ext_vector_type(8)));
typedef float f32x4 __attribute__((ext_vector_type(4)));

__device__ inline u16 f2bf(float x) {
  unsigned u = __float_as_uint(x);
  return (u16)((u + 0x7fffu + ((u >> 16) & 1u)) >> 16);
}
__device__ inline float bf2f(u16 h) { return __uint_as_float(((unsigned)h) << 16); }

// ---------------- prep ----------------
__global__ __launch_bounds__(256) void k_prep(const float* __restrict__ pc,
                                              float* __restrict__ pts,
                                              float* __restrict__ feat0) {
  int idx = blockIdx.x * blockDim.x + threadIdx.x;
  if (idx >= B * N0) return;
  int b = idx / N0, i = idx - b * N0;
  float x = pc[(b * 3 + 0) * N0 + i];
  float y = pc[(b * 3 + 1) * N0 + i];
  float z = pc[(b * 3 + 2) * N0 + i];
  pts[idx * 3 + 0] = x; pts[idx * 3 + 1] = y; pts[idx * 3 + 2] = z;
  feat0[idx * 4 + 0] = x; feat0[idx * 4 + 1] = y; feat0[idx * 4 + 2] = z; feat0[idx * 4 + 3] = 1.0f;
}

// ---------------- pair lists ----------------
__global__ __launch_bounds__(256) void k_pairs(const float* __restrict__ pts,
                                               int* __restrict__ pidx, int* __restrict__ pcnt,
                                               int N) {
  const int r = blockIdx.x * 4 + (threadIdx.x >> 6);
  const int lane = threadIdx.x & 63;
  const int b = r / N;
  const float px = pts[(size_t)r * 3 + 0];
  const float py = pts[(size_t)r * 3 + 1];
  const float pz = pts[(size_t)r * 3 + 2];
  int* row = pidx + (size_t)r * CAP;
  int base = 0;
  for (int j0 = 0; j0 < N; j0 += 64) {
    int j = j0 + lane;
    float dx = px - pts[((size_t)b * N + j) * 3 + 0];
    float dy = py - pts[((size_t)b * N + j) * 3 + 1];
    float dz = pz - pts[((size_t)b * N + j) * 3 + 2];
    float d2 = dx * dx + dy * dy + dz * dz;
    bool keep = d2 <= 0.1228f;
    unsigned long long mk = __ballot(keep);
    int pos = __popcll(mk & ((1ull << lane) - 1ull));
    if (keep) { int s = base + pos; if (s < CAP) row[s] = j; }
    base += __popcll(mk);
  }
  if (lane == 0) pcnt[r] = base < CAP ? base : CAP;
}

// ---------------- stage 1: pair-list contraction -> split bf16 S ----------------
__global__ void k_econtract2(const float* __restrict__ pts, const float* __restrict__ feat,
                             const int* __restrict__ pidx, const int* __restrict__ pcnt,
                             u16* __restrict__ Shi, u16* __restrict__ Slo,
                             int N, int Cin, int K, int Kpad, int mbase) {
  const int g = mbase + blockIdx.x;
  const int b = g / N;
  const int t = threadIdx.x;
  const bool cact = t < Cin;
  const float px = pts[(size_t)g * 3 + 0];
  const float py = pts[(size_t)g * 3 + 1];
  const float pz = pts[(size_t)g * 3 + 2];
  float acc[27];
#pragma unroll
  for (int l = 0; l < 27; ++l) acc[l] = 0.f;
  const int n = pcnt[g];
  const int* row = pidx + (size_t)g * CAP;
  for (int p = 0; p < n; ++p) {
    int j = row[p];
    size_t jb = (size_t)b * N + j;
    float dx = px - pts[jb * 3 + 0];
    float dy = py - pts[jb * 3 + 1];
    float dz = pz - pts[jb * 3 + 2];
    float d2 = dx * dx + dy * dy + dz * dz;
    float base_ = __expf(-512.f * d2);
    float gxv[3] = {__expf(64.f * dx - 2.f), 1.f, __expf(-64.f * dx - 2.f)};
    float gyv[3] = {__expf(64.f * dy - 2.f), 1.f, __expf(-64.f * dy - 2.f)};
    float gzv[3] = {__expf(64.f * dz - 2.f), 1.f, __expf(-64.f * dz - 2.f)};
    float fv = cact ? feat[jb * Cin + t] : 0.f;
#pragma unroll
    for (int a = 0; a < 3; ++a) {
      float ba = base_ * gxv[a];
#pragma unroll
      for (int b2 = 0; b2 < 3; ++b2) {
        float bab = ba * gyv[b2];
#pragma unroll
        for (int c2 = 0; c2 < 3; ++c2) {
          int l = a * 9 + b2 * 3 + c2;
          acc[l] = fmaf(bab * gzv[c2], fv, acc[l]);
        }
      }
    }
  }
  size_t rowo = (size_t)blockIdx.x * Kpad;
  if (cact) {
#pragma unroll
    for (int l = 0; l < 27; ++l) {
      float v = acc[l];
      u16 h = f2bf(v);
      u16 lo = f2bf(v - bf2f(h));
      Shi[rowo + (size_t)l * Cin + t] = h;
      Slo[rowo + (size_t)l * Cin + t] = lo;
    }
  }
  if (Kpad > K && t >= Cin && t < Cin + (Kpad - K)) {
    size_t po = rowo + K + (t - Cin);
    Shi[po] = 0; Slo[po] = 0;
  }
}

// ---------------- W split+transpose ----------------
__global__ __launch_bounds__(256) void k_wsplit(const float* __restrict__ W,
                                                u16* __restrict__ Whi, u16* __restrict__ Wlo,
                                                int K, int Kpad, int Cout, int nbase) {
  __shared__ float tile[32][65];
  const int t = threadIdx.x;
  const int k0 = blockIdx.x * 32, n0 = blockIdx.y * 64;
#pragma unroll
  for (int v = 0; v < 2; ++v) {
    int kk = (t >> 4) + v * 16;
    int nn = (t & 15) * 4;
    int gk = k0 + kk;
    float4 val = make_float4(0.f, 0.f, 0.f, 0.f);
    if (gk < K) val = *(const float4*)(W + (size_t)gk * Cout + nbase + n0 + nn);
    tile[kk][nn + 0] = val.x; tile[kk][nn + 1] = val.y;
    tile[kk][nn + 2] = val.z; tile[kk][nn + 3] = val.w;
  }
  __syncthreads();
  const int n_ = t >> 2, kq = (t & 3) * 8;
  union { u16 u[8]; uint4 v; } Uh, Ul;
#pragma unroll
  for (int j = 0; j < 8; ++j) {
    float x = tile[kq + j][n_];
    u16 h = f2bf(x);
    Uh.u[j] = h;
    Ul.u[j] = f2bf(x - bf2f(h));
  }
  size_t o = (size_t)(n0 + n_) * Kpad + k0 + kq;
  *(uint4*)(Whi + o) = Uh.v;
  *(uint4*)(Wlo + o) = Ul.v;
}

// ---------------- stage 2: MFMA GEMM, 8 waves, in-block split-K(2) ----------------
__global__ __launch_bounds__(512) void k_gemm_mfma(const u16* __restrict__ Shi,
                                                   const u16* __restrict__ Slo,
                                                   const u16* __restrict__ Whi,
                                                   const u16* __restrict__ Wlo,
                                                   const float* __restrict__ bias,
                                                   float* __restrict__ out,
                                                   int Kpad, int Nstride, float scale) {
  __shared__ u16 As[2][2][32][40];   // [k-half][hi/lo][m][k]
  __shared__ u16 Bs[2][2][64][40];
  __shared__ float xch[4][64][8];
  const int t = threadIdx.x;
  const int h = t >> 8;              // staging k-half
  const int tl = t & 255;
  const int nb = blockIdx.x * 64;
  const int m0 = blockIdx.y * 32;
  const int l = t & 63, w = t >> 6;  // wave 0..7
  const int ks = w >> 2, wq = w & 3;
  const int wm = (wq >> 1) * 16, wn = (wq & 1) * 32;
  const int la = l & 15, lg = l >> 4;
  const int ar = tl >> 3, akq = (tl & 7) * 4;
  const int bn = tl >> 2, bkq = (tl & 3) * 8;
  const size_t aBase = (size_t)(m0 + ar) * Kpad + h * 32 + akq;
  const size_t bBase = (size_t)(nb + bn) * Kpad + h * 32 + bkq;
  f32x4 acc0 = {0.f, 0.f, 0.f, 0.f}, acc1 = {0.f, 0.f, 0.f, 0.f};

  for (int k0 = 0; k0 < Kpad; k0 += 64) {
    *(ushort4*)&As[h][0][ar][akq] = *(const ushort4*)(Shi + aBase + k0);
    *(ushort4*)&As[h][1][ar][akq] = *(const ushort4*)(Slo + aBase + k0);
    *(uint4*)&Bs[h][0][bn][bkq] = *(const uint4*)(Whi + bBase + k0);
    *(uint4*)&Bs[h][1][bn][bkq] = *(const uint4*)(Wlo + bBase + k0);
    __syncthreads();
    bf16x8 ah = *(const bf16x8*)&As[ks][0][wm + la][lg * 8];
    bf16x8 al = *(const bf16x8*)&As[ks][1][wm + la][lg * 8];
    bf16x8 bh0 = *(const bf16x8*)&Bs[ks][0][wn + la][lg * 8];
    bf16x8 bl0 = *(const bf16x8*)&Bs[ks][1][wn + la][lg * 8];
    bf16x8 bh1 = *(const bf16x8*)&Bs[ks][0][wn + 16 + la][lg * 8];
    bf16x8 bl1 = *(const bf16x8*)&Bs[ks][1][wn + 16 + la][lg * 8];
    acc0 = __builtin_amdgcn_mfma_f32_16x16x32_bf16(ah, bh0, acc0, 0, 0, 0);
    acc1 = __builtin_amdgcn_mfma_f32_16x16x32_bf16(ah, bh1, acc1, 0, 0, 0);
    acc0 = __builtin_amdgcn_mfma_f32_16x16x32_bf16(al, bh0, acc0, 0, 0, 0);
    acc1 = __builtin_amdgcn_mfma_f32_16x16x32_bf16(al, bh1, acc1, 0, 0, 0);
    acc0 = __builtin_amdgcn_mfma_f32_16x16x32_bf16(ah, bl0, acc0, 0, 0, 0);
    acc1 = __builtin_amdgcn_mfma_f32_16x16x32_bf16(ah, bl1, acc1, 0, 0, 0);
    __syncthreads();
  }
  if (w >= 4) {
#pragma unroll
    for (int r = 0; r < 4; ++r) { xch[wq][l][r] = acc0[r]; xch[wq][l][r + 4] = acc1[r]; }
  }
  __syncthreads();
  if (w < 4) {
#pragma unroll
    for (int r = 0; r < 4; ++r) { acc0[r] += xch[wq][l][r]; acc1[r] += xch[wq][l][r + 4]; }
#pragma unroll
    for (int r = 0; r < 4; ++r) {
      int gm = m0 + wm + lg * 4 + r;
      int gn0 = nb + wn + la;
      float v0 = fmaf(acc0[r], scale, bias[gn0]);
      out[(size_t)gm * Nstride + gn0] = fmaxf(v0, 0.f);
      int gn1 = gn0 + 16;
      float v1 = fmaf(acc1[r], scale, bias[gn1]);
      out[(size_t)gm * Nstride + gn1] = fmaxf(v1, 0.f);
    }
  }
}

// ---------------- FPS ----------------
template <int CTRL>
__device__ __forceinline__ void dppmax(unsigned& hi, unsigned& lo) {
  unsigned thi = (unsigned)__builtin_amdgcn_update_dpp(0, (int)hi, CTRL, 0xF, 0xF, true);
  unsigned tlo = (unsigned)__builtin_amdgcn_update_dpp(0, (int)lo, CTRL, 0xF, 0xF, true);
  bool g = (thi > hi) || (thi == hi && tlo > lo);
  hi = g ? thi : hi;
  lo = g ? tlo : lo;
}

template <int NQ> __device__ __forceinline__ float treesel(const float* q, int qsel);
template <> __device__ __forceinline__ float treesel<1>(const float* q, int) { return q[0]; }
template <> __device__ __forceinline__ float treesel<4>(const float* q, int qsel) {
  bool e0 = qsel & 1, e1 = qsel & 2;
  float a0 = e0 ? q[1] : q[0], a1 = e0 ? q[3] : q[2];
  return e1 ? a1 : a0;
}
template <> __device__ __forceinline__ float treesel<16>(const float* q, int qsel) {
  bool e0 = qsel & 1, e1 = qsel & 2, e2 = qsel & 4, e3 = qsel & 8;
  float b0 = e0 ? q[1] : q[0],  b1 = e0 ? q[3] : q[2];
  float b2 = e0 ? q[5] : q[4],  b3 = e0 ? q[7] : q[6];
  float b4 = e0 ? q[9] : q[8],  b5 = e0 ? q[11] : q[10];
  float b6 = e0 ? q[13] : q[12], b7 = e0 ? q[15] : q[14];
  float c0 = e1 ? b1 : b0, c1 = e1 ? b3 : b2, c2 = e1 ? b5 : b4, c3 = e1 ? b7 : b6;
  float d0 = e2 ? c1 : c0, d1 = e2 ? c3 : c2;
  return e3 ? d1 : d0;
}

template <int N>
__global__ __launch_bounds__(64) void k_fps(const float* __restrict__ pts,
                                            float* __restrict__ centers, int m) {
  constexpr int NQ = N / 64;
  const int b = blockIdx.x;
  const int lane = threadIdx.x;
  const float* P = pts + (size_t)b * N * 3;
  float qx[NQ], qy[NQ], qz[NQ], d[NQ];
  float x0 = P[0], y0 = P[1], z0 = P[2];
  float lbest = -1.f; int lj = 0;
#pragma unroll
  for (int q = 0; q < NQ; ++q) {
    int j = lane + q * 64;
    float x = P[j * 3 + 0], y = P[j * 3 + 1], z = P[j * 3 + 2];
    qx[q] = x; qy[q] = y; qz[q] = z;
    float dx = __fsub_rn(x, x0), dy = __fsub_rn(y, y0), dz = __fsub_rn(z, z0);
    float dd = __fadd_rn(__fadd_rn(__fmul_rn(dx, dx), __fmul_rn(dy, dy)), __fmul_rn(dz, dz));
    d[q] = dd;
    bool g = dd > lbest; lbest = g ? dd : lbest; lj = g ? j : lj;
  }
  if (lane == 0) {
    centers[(size_t)b * m * 3 + 0] = x0;
    centers[(size_t)b * m * 3 + 1] = y0;
    centers[(size_t)b * m * 3 + 2] = z0;
  }
  for (int it = 1; it < m; ++it) {
    unsigned hi = __float_as_uint(lbest), lo = ~(unsigned)lj;
    dppmax<0xB1>(hi, lo);
    dppmax<0x4E>(hi, lo);
    dppmax<0x141>(hi, lo);
    dppmax<0x140>(hi, lo);
    dppmax<0x142>(hi, lo);
    dppmax<0x143>(hi, lo);
    int wj = ~__builtin_amdgcn_readlane((int)lo, 63);
    int qsel = wj >> 6, sl = wj & 63;
    float sx = treesel<NQ>(qx, qsel);
    float sy = treesel<NQ>(qy, qsel);
    float sz = treesel<NQ>(qz, qsel);
    float cx = __uint_as_float((unsigned)__builtin_amdgcn_readlane((int)__float_as_uint(sx), sl));
    float cy = __uint_as_float((unsigned)__builtin_amdgcn_readlane((int)__float_as_uint(sy), sl));
    float cz = __uint_as_float((unsigned)__builtin_amdgcn_readlane((int)__float_as_uint(sz), sl));
    if (lane == 0) {
      centers[((size_t)b * m + it) * 3 + 0] = cx;
      centers[((size_t)b * m + it) * 3 + 1] = cy;
      centers[((size_t)b * m + it) * 3 + 2] = cz;
    }
    lbest = -1.f; lj = 0;
#pragma unroll
    for (int q = 0; q < NQ; ++q) {
      int j = lane + q * 64;
      float dx = __fsub_rn(qx[q], cx), dy = __fsub_rn(qy[q], cy), dz = __fsub_rn(qz[q], cz);
      float nd = __fadd_rn(__fadd_rn(__fmul_rn(dx, dx), __fmul_rn(dy, dy)), __fmul_rn(dz, dz));
      float dn = fminf(d[q], nd);
      d[q] = dn;
      bool g = dn > lbest; lbest = g ? dn : lbest; lj = g ? j : lj;
    }
  }
}

// ---------------- assignment ----------------
__global__ __launch_bounds__(256) void k_assign(const float* __restrict__ pts,
                                                const float* __restrict__ centers,
                                                int* __restrict__ assign, int N, int m) {
  int idx = blockIdx.x * blockDim.x + threadIdx.x;
  if (idx >= B * N) return;
  int b = idx / N;
  float px = pts[(size_t)idx * 3 + 0], py = pts[(size_t)idx * 3 + 1], pz = pts[(size_t)idx * 3 + 2];
  float best = 3.4e38f; int bk = 0;
  for (int k = 0; k < m; ++k) {
    float dx = __fsub_rn(px, centers[((size_t)b * m + k) * 3 + 0]);
    float dy = __fsub_rn(py, centers[((size_t)b * m + k) * 3 + 1]);
    float dz = __fsub_rn(pz, centers[((size_t)b * m + k) * 3 + 2]);
    float dd = __fadd_rn(__fadd_rn(__fmul_rn(dx, dx), __fmul_rn(dy, dy)), __fmul_rn(dz, dz));
    if (dd < best) { best = dd; bk = k; }
  }
  assign[idx] = bk;
}

// segment max via int atomicMax (values post-relu >= 0; init bits 0xFFFFFFFF = -1)
__global__ __launch_bounds__(256) void k_segmax(const float* __restrict__ feat,
                                                const int* __restrict__ assign,
                                                float* __restrict__ pooled,
                                                int N, int m, int C) {
  int idx = blockIdx.x * blockDim.x + threadIdx.x;
  if (idx >= B * N * C) return;
  int b = idx / (N * C);
  int r = idx - b * N * C;
  int i = r / C;
  int c = r - i * C;
  int a = assign[b * N + i];
  atomicMax((int*)&pooled[((size_t)b * m + a) * C + c], __float_as_int(feat[idx]));
}

// ---------------- FC ----------------
template <int K, int COUT, bool BNR>
__global__ __launch_bounds__(256) void k_fc(const float* __restrict__ x,
                                            const float* __restrict__ w,
                                            const float* __restrict__ g,
                                            const float* __restrict__ be,
                                            float* __restrict__ out) {
  __shared__ float ys[8][33];
  int t = threadIdx.x;
  int n = t >> 5, cl = t & 31;
  int c = blockIdx.x * 32 + cl;
  float acc = 0.f;
  if (c < COUT) {
    const float* xr = x + n * K;
    float a0 = 0.f, a1 = 0.f, a2 = 0.f, a3 = 0.f;
    for (int k = 0; k < K; k += 4) {
      a0 = fmaf(xr[k + 0], w[(size_t)(k + 0) * COUT + c], a0);
      a1 = fmaf(xr[k + 1], w[(size_t)(k + 1) * COUT + c], a1);
      a2 = fmaf(xr[k + 2], w[(size_t)(k + 2) * COUT + c], a2);
      a3 = fmaf(xr[k + 3], w[(size_t)(k + 3) * COUT + c], a3);
    }
    acc = (a0 + a1) + (a2 + a3);
  }
  ys[n][cl] = acc;
  __syncthreads();
  if (c >= COUT) return;
  if (BNR) {
    float mu = 0.f;
#pragma unroll
    for (int q = 0; q < 8; ++q) mu += ys[q][cl];
    mu *= 0.125f;
    float var = 0.f;
#pragma unroll
    for (int q = 0; q < 8; ++q) { float dv = ys[q][cl] - mu; var = fmaf(dv, dv, var); }
    var *= 0.125f;
    float rs = 1.f / sqrtf(var + 1e-5f);
    float v = g[c] * (acc - mu) * rs + be[c];
    out[n * COUT + c] = fmaxf(v, 0.f);
  } else {
    out[n * COUT + c] = acc + be[c];
  }
}

// ---------------- launcher ----------------
extern "C" void kernel_launch(void* const* d_in, const int* in_sizes, int n_in,
                              void* d_out, int out_size, void* d_ws, size_t ws_size,
                              hipStream_t stream) {
  (void)in_sizes; (void)n_in; (void)out_size;
  const float* pc = (const float*)d_in[0];
  const float* Wc[6]; const float* bc[6];
  for (int l = 0; l < 6; ++l) { Wc[l] = (const float*)d_in[1 + 2 * l]; bc[l] = (const float*)d_in[2 + 2 * l]; }
  const float* w1 = (const float*)d_in[13];
  const float* g1 = (const float*)d_in[14];
  const float* be1 = (const float*)d_in[15];
  const float* w2 = (const float*)d_in[16];
  const float* g2 = (const float*)d_in[17];
  const float* be2 = (const float*)d_in[18];
  const float* w3 = (const float*)d_in[19];
  const float* b3 = (const float*)d_in[20];

  float* ws = (float*)d_ws;
  size_t o = 0;
  auto A = [&](size_t n) { size_t r = o; o += (n + 63) & ~(size_t)63; return r; };
  const size_t PTS0 = A((size_t)B * 1024 * 3);
  const size_t PTS1 = A((size_t)B * 256 * 3);
  const size_t PTS2 = A((size_t)B * 64 * 3);
  const size_t PTS3 = A((size_t)B * 3);
  const size_t F0  = A((size_t)B * 1024 * 4);
  const size_t FB1 = A((size_t)B * 1024 * 64);
  const size_t FB2 = A((size_t)B * 1024 * 64);
  const size_t FB3 = A((size_t)B * 256 * 64);
  const size_t FB4 = A((size_t)B * 256 * 128);
  const size_t FB5 = A((size_t)B * 256 * 128);
  const size_t FB6 = A((size_t)B * 64 * 128);
  const size_t FB7 = A((size_t)B * 64 * 256);
  const size_t FB8 = A((size_t)B * 64 * 1024);
  const size_t FB9 = A((size_t)B * 1024);
  const size_t ASSIGN = A((size_t)B * 1024);
  const size_t Y1 = A((size_t)8 * 512);
  const size_t Y2 = A((size_t)8 * 256);
  const size_t PIDX = A((size_t)B * 1024 * CAP);
  const size_t PCNT = A((size_t)B * 1024);
  const size_t dynB = o * sizeof(float);

  int* pidx = (int*)(ws + PIDX);
  int* pcnt = (int*)(ws + PCNT);

  k_prep<<<dim3((B * N0 + 255) / 256), dim3(256), 0, stream>>>(pc, ws + PTS0, ws + F0);

  auto conv = [&](size_t ptsOff, size_t finOff, size_t foutOff, int Npts, int Cin, int Cout,
                  const float* W, const float* bias) {
    const int M = B * Npts;
    const int K = 27 * Cin;
    const int Kpad = (K + 31) & ~31;
    const size_t availB = (ws_size > dynB) ? ws_size - dynB : 0;
    int NCc = Cout;
    while (NCc > 128 && (size_t)NCc * Kpad * 4 + (size_t)M * Kpad * 4 > availB) NCc >>= 1;
    while (NCc > 64 && (size_t)NCc * Kpad * 4 + (size_t)32 * Kpad * 4 > availB) NCc >>= 1;
    const size_t wtB = (size_t)NCc * Kpad * 4;
    const size_t sB = (availB > wtB) ? availB - wtB : 0;
    long mc = (long)(sB / ((size_t)Kpad * 4)) & ~31L;
    int Mc = (int)((mc < (long)M) ? mc : (long)M);
    if (Mc < 32) Mc = 32;
    u16* Shi = (u16*)((char*)d_ws + dynB);
    u16* Slo = Shi + (size_t)Mc * Kpad;
    u16* Whi = Shi + (size_t)2 * Mc * Kpad;
    u16* Wlo = Whi + (size_t)NCc * Kpad;
    const int nch = (Cout + NCc - 1) / NCc;
    const int mch = (M + Mc - 1) / Mc;
    const float scale = 1.f / (float)Npts;
    const int blk = (Cin <= 64) ? 64 : Cin;
    auto econ = [&](int mb0, int mcur) {
      k_econtract2<<<dim3(mcur), dim3(blk), 0, stream>>>(ws + ptsOff, ws + finOff, pidx, pcnt,
                                                         Shi, Slo, Npts, Cin, K, Kpad, mb0);
    };
    auto wsp = [&](int nb0, int ncur) {
      k_wsplit<<<dim3(Kpad / 32, ncur / 64), dim3(256), 0, stream>>>(W, Whi, Wlo, K, Kpad, Cout, nb0);
    };
    auto gem = [&](int nb0, int ncur, int mb0, int mcur) {
      float* outp = ws + foutOff + (size_t)mb0 * Cout + nb0;
      k_gemm_mfma<<<dim3(ncur / 64, mcur / 32), dim3(512), 0, stream>>>(
          Shi, Slo, Whi, Wlo, bias + nb0, outp, Kpad, Cout, scale);
    };
    if (mch == 1) {
      econ(0, M);
      for (int nc = 0; nc < nch; ++nc) {
        int nb0 = nc * NCc;
        int ncur = ((Cout - nb0) < NCc) ? (Cout - nb0) : NCc;
        wsp(nb0, ncur);
        gem(nb0, ncur, 0, M);
      }
    } else if (nch == 1) {
      wsp(0, Cout);
      for (int mcb = 0; mcb < mch; ++mcb) {
        int mb0 = mcb * Mc;
        int mcur = ((M - mb0) < Mc) ? (M - mb0) : Mc;
        econ(mb0, mcur);
        gem(0, Cout, mb0, mcur);
      }
    } else {
      for (int nc = 0; nc < nch; ++nc) {
        int nb0 = nc * NCc;
        int ncur = ((Cout - nb0) < NCc) ? (Cout - nb0) : NCc;
        wsp(nb0, ncur);
        for (int mcb = 0; mcb < mch; ++mcb) {
          int mb0 = mcb * Mc;
          int mcur = ((M - mb0) < Mc) ? (M - mb0) : Mc;
          econ(mb0, mcur);
          gem(nb0, ncur, mb0, mcur);
        }
      }
    }
  };

  // ---- level 0 ----
  k_pairs<<<dim3(B * 1024 / 4), dim3(256), 0, stream>>>(ws + PTS0, pidx, pcnt, 1024);
  conv(PTS0, F0, FB1, 1024, 4, 64, Wc[0], bc[0]);
  conv(PTS0, FB1, FB2, 1024, 64, 64, Wc[1], bc[1]);
  k_fps<1024><<<dim3(B), dim3(64), 0, stream>>>(ws + PTS0, ws + PTS1, 256);
  k_assign<<<dim3((B * 1024 + 255) / 256), dim3(256), 0, stream>>>(ws + PTS0, ws + PTS1, (int*)(ws + ASSIGN), 1024, 256);
  hipMemsetAsync(ws + FB3, 0xFF, (size_t)B * 256 * 64 * 4, stream);
  k_segmax<<<dim3((B * 1024 * 64 + 255) / 256), dim3(256), 0, stream>>>(ws + FB2, (int*)(ws + ASSIGN), ws + FB3, 1024, 256, 64);
  // ---- level 1 ----
  k_pairs<<<dim3(B * 256 / 4), dim3(256), 0, stream>>>(ws + PTS1, pidx, pcnt, 256);
  conv(PTS1, FB3, FB4, 256, 64, 128, Wc[2], bc[2]);
  conv(PTS1, FB4, FB5, 256, 128, 128, Wc[3], bc[3]);
  k_fps<256><<<dim3(B), dim3(64), 0, stream>>>(ws + PTS1, ws + PTS2, 64);
  k_assign<<<dim3((B * 256 + 255) / 256), dim3(256), 0, stream>>>(ws + PTS1, ws + PTS2, (int*)(ws + ASSIGN), 256, 64);
  hipMemsetAsync(ws + FB6, 0xFF, (size_t)B * 64 * 128 * 4, stream);
  k_segmax<<<dim3((B * 256 * 128 + 255) / 256), dim3(256), 0, stream>>>(ws + FB5, (int*)(ws + ASSIGN), ws + FB6, 256, 64, 128);
  // ---- level 2 ----
  k_pairs<<<dim3(B * 64 / 4), dim3(256), 0, stream>>>(ws + PTS2, pidx, pcnt, 64);
  conv(PTS2, FB6, FB7, 64, 128, 256, Wc[4], bc[4]);
  conv(PTS2, FB7, FB8, 64, 256, 1024, Wc[5], bc[5]);
  k_fps<64><<<dim3(B), dim3(64), 0, stream>>>(ws + PTS2, ws + PTS3, 1);
  k_assign<<<dim3((B * 64 + 255) / 256), dim3(256), 0, stream>>>(ws + PTS2, ws + PTS3, (int*)(ws + ASSIGN), 64, 1);
  hipMemsetAsync(ws + FB9, 0xFF, (size_t)B * 1024 * 4, stream);
  k_segmax<<<dim3((B * 64 * 1024 + 255) / 256), dim3(256), 0, stream>>>(ws + FB8, (int*)(ws + ASSIGN), ws + FB9, 64, 1, 1024);
  // ---- FC head ----
  k_fc<1024, 512, true><<<dim3(512 / 32), dim3(256), 0, stream>>>(ws + FB9, w1, g1, be1, ws + Y1);
  k_fc<512, 256, true><<<dim3(256 / 32), dim3(256), 0, stream>>>(ws + Y1, w2, g2, be2, ws + Y2);
  k_fc<256, 40, false><<<dim3(2), dim3(256), 0, stream>>>(ws + Y2, w3, nullptr, b3, (float*)d_out);
}